// Round 20
// baseline (134.633 us; speedup 1.0000x reference)
//
#include <hip/hip_runtime.h>
#include <hip/hip_bf16.h>
#include <cstdint>
#include <cstddef>

// Problem constants (B=1, T=2048, C=2048, H=32, KVH=8, D=64)
#define T_SEQ 2048
#define C_DIM 2048
#define NQKV  3072   // H*D + 2*KVH*D
#define HQ    32
#define KVH_  8
#define D_HEAD 64

using bf16x8 = __attribute__((ext_vector_type(8))) __bf16;
using f32x4  = __attribute__((ext_vector_type(4))) float;

typedef const __attribute__((address_space(1))) void* gas_ptr;
typedef __attribute__((address_space(3))) void* las_ptr;
#define GLOAD_LDS16(g, l) __builtin_amdgcn_global_load_lds((gas_ptr)(g), (las_ptr)(l), 16, 0, 0)

static __device__ __forceinline__ unsigned short f2bf(float f) {
  union { float f; unsigned int u; } v; v.f = f;
  unsigned int u = v.u;
  unsigned int r = u + 0x7fffu + ((u >> 16) & 1u);   // RNE
  return (unsigned short)(r >> 16);
}
static __device__ __forceinline__ float bf2f(unsigned short s) {
  union { unsigned int u; float f; } v; v.u = ((unsigned int)s) << 16;
  return v.f;
}
static __device__ __forceinline__ bf16x8 load8(const unsigned short* p) {
  return *reinterpret_cast<const bf16x8*>(p);
}
static __device__ __forceinline__ f32x4 mfma16(bf16x8 a, bf16x8 b, f32x4 c) {
  return __builtin_amdgcn_mfma_f32_16x16x32_bf16(a, b, c, 0, 0, 0);
}

// Heavy-first static schedule for attn split-K blocks (40 per head):
// f -> (qg, seg); a segment is 512 keys (= 16 tiles of 32 keys).
static __device__ const unsigned char kF2QG[40] = {
    15, 15, 15, 15, 14, 14, 14, 13, 13, 13, 12, 12, 12, 11, 11,
    10, 10, 9, 9, 8, 8, 7, 7, 6, 5, 4, 3,
    14, 11, 6, 2, 13, 10, 5, 1, 12, 9, 8, 4, 0};
static __device__ const unsigned char kF2SEG[40] = {
    0, 1, 2, 3, 0, 1, 2, 0, 1, 2, 0, 1, 2, 0, 1,
    0, 1, 0, 1, 0, 1, 0, 1, 0, 0, 0, 0,
    3, 2, 1, 0, 3, 2, 1, 0, 3, 2, 2, 1, 0};
// Inverse: qg -> f index of each of its segments.
static __device__ const unsigned char kQGF[16][4] = {
    {39, 0, 0, 0}, {34, 0, 0, 0}, {30, 0, 0, 0}, {26, 0, 0, 0},
    {25, 38, 0, 0}, {24, 33, 0, 0}, {23, 29, 0, 0}, {21, 22, 0, 0},
    {19, 20, 37, 0}, {17, 18, 36, 0}, {15, 16, 32, 0}, {13, 14, 28, 0},
    {10, 11, 12, 35}, {7, 8, 9, 31}, {4, 5, 6, 27}, {0, 1, 2, 3}};

// ---------------------------------------------------------------------------
// cast_x: x f32 -> bf16 row-major, 8 elems/thread
// ---------------------------------------------------------------------------
__global__ __launch_bounds__(256) void cast_x_kernel(
    const float* __restrict__ x, unsigned short* __restrict__ xh) {
  const int i = (blockIdx.x * 256 + threadIdx.x) * 8;
  const float4 a = *reinterpret_cast<const float4*>(x + i);
  const float4 b = *reinterpret_cast<const float4*>(x + i + 4);
  ushort h[8];
  h[0] = f2bf(a.x); h[1] = f2bf(a.y); h[2] = f2bf(a.z); h[3] = f2bf(a.w);
  h[4] = f2bf(b.x); h[5] = f2bf(b.y); h[6] = f2bf(b.z); h[7] = f2bf(b.w);
  *reinterpret_cast<uint4*>(xh + i) = *reinterpret_cast<const uint4*>(h);
}

// ---------------------------------------------------------------------------
// Transpose + f32->bf16 cast: src[R][C] -> dst[C][R]
// ---------------------------------------------------------------------------
__global__ __launch_bounds__(256) void transpose_cast_kernel(
    const float* __restrict__ src, unsigned short* __restrict__ dhi, int R, int C) {
  __shared__ float tile[64][65];
  const int r0 = blockIdx.y * 64, c0 = blockIdx.x * 64;
  const int tid = threadIdx.x;
  const int lr = tid >> 4, lc = (tid & 15) * 4;
  for (int i = 0; i < 4; ++i) {
    const int row = lr + i * 16;
    const float4 v = *reinterpret_cast<const float4*>(&src[(size_t)(r0 + row) * C + c0 + lc]);
    tile[row][lc + 0] = v.x; tile[row][lc + 1] = v.y;
    tile[row][lc + 2] = v.z; tile[row][lc + 3] = v.w;
  }
  __syncthreads();
  for (int i = 0; i < 4; ++i) {
    const int n = lr + i * 16;
    ushort4 h;
    h.x = f2bf(tile[lc + 0][n]); h.y = f2bf(tile[lc + 1][n]);
    h.z = f2bf(tile[lc + 2][n]); h.w = f2bf(tile[lc + 3][n]);
    *reinterpret_cast<ushort4*>(&dhi[(size_t)(c0 + n) * R + r0 + lc]) = h;
  }
}

// ---------------------------------------------------------------------------
// GEMM1: qkv = bf16(x) @ bf16(Wqkv). BM=64, BN=128 -> 768 blocks (grid fill).
// 2x2 waves, each 32x64 (full head per wave for RoPE). BK=64, XOR swizzle.
// Epilogue: RoPE; q pre-scaled by 0.125*log2(e) (exp2-fold).
// ---------------------------------------------------------------------------
__global__ __launch_bounds__(256, 2) void gemm1_kernel(
    const unsigned short* __restrict__ Xh, const unsigned short* __restrict__ BTh,
    const float* __restrict__ cosb, const float* __restrict__ sinb,
    unsigned short* __restrict__ qkv) {
  __shared__ unsigned short Ah[64 * 64], Bh[128 * 64];
  const int tid = threadIdx.x;
  const int orig = (int)blockIdx.y * 24 + (int)blockIdx.x;   // 768 blocks
  const int wgid = (orig & 7) * 96 + (orig >> 3);            // bijective XCD swz
  const int n0 = (wgid % 24) * 128, m0 = (wgid / 24) * 64;
  const int lane = tid & 63, wave = tid >> 6;
  const int wm = wave >> 1, wn = wave & 1;      // 2x2 waves, 32x64 per wave
  const int lrow = lane & 15, g = lane >> 4;
  const int srow8 = lane >> 3, pchunk = lane & 7;
  const int swz = lrow & 7;
  f32x4 acc[2][4] = {};
  for (int kb = 0; kb < C_DIM; kb += 64) {
    __syncthreads();
    for (int p = 0; p < 2; ++p) {               // A: 64 rows
      const int row = (p * 4 + wave) * 8 + srow8;
      const int gcol = (pchunk ^ srow8) * 8;
      GLOAD_LDS16(&Xh[(size_t)(m0 + row) * C_DIM + kb + gcol],
                  &Ah[row * 64 + pchunk * 8]);
    }
    for (int p = 0; p < 4; ++p) {               // B: 128 rows
      const int row = (p * 4 + wave) * 8 + srow8;
      const int gcol = (pchunk ^ srow8) * 8;
      GLOAD_LDS16(&BTh[(size_t)(n0 + row) * C_DIM + kb + gcol],
                  &Bh[row * 64 + pchunk * 8]);
    }
    __syncthreads();
    for (int kk = 0; kk < 2; ++kk) {
      bf16x8 ah[2], bh[4];
      const int cc = ((kk * 4 + g) ^ swz) * 8;
      for (int i = 0; i < 2; ++i)
        ah[i] = load8(&Ah[(wm * 32 + i * 16 + lrow) * 64 + cc]);
      for (int i = 0; i < 4; ++i)
        bh[i] = load8(&Bh[(wn * 64 + i * 16 + lrow) * 64 + cc]);
      for (int mi = 0; mi < 2; ++mi)
        for (int ni = 0; ni < 4; ++ni)
          acc[mi][ni] = mfma16(ah[mi], bh[ni], acc[mi][ni]);
    }
  }
  const int colbase = n0 + wn * 64;                 // 64-aligned => one head
  const bool isv = colbase >= (C_DIM + KVH_ * D_HEAD);
  // q scale folds softmax's 1/8 AND log2(e) so attn uses raw v_exp (base 2).
  const float qsc = (colbase < C_DIM) ? 0.18033688011112042f : 1.0f;
  for (int mi = 0; mi < 2; ++mi) {
    for (int r = 0; r < 4; ++r) {
      const int trow = m0 + wm * 32 + mi * 16 + g * 4 + r;
      if (!isv) {
        for (int ni = 0; ni < 2; ++ni) {
          const int dh = ni * 16 + lrow;            // 0..31
          const float c = cosb[trow * 32 + dh];
          const float s = sinb[trow * 32 + dh];
          const float a = bf2f(f2bf(acc[mi][ni][r]));       // ref: bf16 then f32 rope
          const float b = bf2f(f2bf(acc[mi][ni + 2][r]));
          qkv[(size_t)trow * NQKV + colbase + dh]      = f2bf((a * c - b * s) * qsc);
          qkv[(size_t)trow * NQKV + colbase + dh + 32] = f2bf((a * s + b * c) * qsc);
        }
      } else {
        for (int ni = 0; ni < 4; ++ni)
          qkv[(size_t)trow * NQKV + colbase + ni * 16 + lrow] = f2bf(acc[mi][ni][r]);
      }
    }
  }
}

// ---------------------------------------------------------------------------
// V transpose: Vt[kvh*64+d][t] = qkv[t][2560 + kvh*64 + d]
// ---------------------------------------------------------------------------
__global__ __launch_bounds__(256) void vt_kernel(const unsigned short* __restrict__ qkv,
                                                 unsigned short* __restrict__ vt) {
  __shared__ unsigned short tile[64][72];
  const int t0 = blockIdx.x * 64, j0 = blockIdx.y * 64;
  const int tid = threadIdx.x;
  const int lr = tid >> 4, lc = (tid & 15) * 4;
  for (int i = 0; i < 4; ++i) {
    const int row = lr + i * 16;
    const ushort4 v = *reinterpret_cast<const ushort4*>(
        &qkv[(size_t)(t0 + row) * NQKV + (C_DIM + KVH_ * D_HEAD) + j0 + lc]);
    *reinterpret_cast<ushort4*>(&tile[row][lc]) = v;
  }
  __syncthreads();
  for (int i = 0; i < 4; ++i) {
    const int j = lr + i * 16;
    ushort4 v;
    v.x = tile[lc + 0][j]; v.y = tile[lc + 1][j];
    v.z = tile[lc + 2][j]; v.w = tile[lc + 3][j];
    *reinterpret_cast<ushort4*>(&vt[(size_t)(j0 + j) * T_SEQ + t0 + lc]) = v;
  }
}

// ---------------------------------------------------------------------------
// Flash attention, split-K. Round-20: KVBLK 64 -> 32 (pure parameter change;
// per-key work identical). LDS 51.2 -> 26.2 KB -> 6 blocks/CU = 24 waves/CU
// (2x TLP on the same latency chain). K tile [32 k][64 d]; V tile [64 d][32 t]
// with 4-chunk XOR swizzle (both-sides involution). Segment = 16 tiles.
// Epilogue transposes per-qs through the (smaller) plds.
// ---------------------------------------------------------------------------
__global__ __launch_bounds__(256, 3) void attn_seg_kernel(
    const unsigned short* __restrict__ qkv, const unsigned short* __restrict__ Vt,
    unsigned short* __restrict__ po, float2* __restrict__ pml) {
  __shared__ unsigned short kbuf[2][32 * 64];     // [buf][k-row][d] (chunk-swz)
  __shared__ unsigned short vbuf[2][64 * 32];     // [buf][d-row][t] (chunk-swz)
  __shared__ unsigned short plds[4][2][16][40];   // [wave][qs][q-row][32k + pad]
  const int f = blockIdx.x, h = blockIdx.y;
  const int qg = kF2QG[f];
  const int seg = kF2SEG[f];
  const int slot = h * 40 + f;
  const int tid = threadIdx.x;
  const int wave = tid >> 6, lane = tid & 63;
  const int kvh = h >> 2;
  const int q0 = qg * 128 + wave * 32;
  const int lrow = lane & 15, g = lane >> 4;

  const int t0 = seg * 16;                        // 32-key tiles
  const int t1 = min(t0 + 16, 4 * qg + 4);        // tiles [t0, t1)

  // K staging map: 32 rows x 8 chunks; wave covers rows wave*8..wave*8+7
  const int ksrow = lane >> 3;                    // 0..7
  const int kchunk = (lane & 7) ^ ksrow;          // pre-swizzled source chunk
  // V staging map: 64 rows x 4 chunks; wave covers rows wave*16..wave*16+15
  const int vsrow = lane >> 2;                    // 0..15
  const int vchunk = (lane & 3) ^ (vsrow & 3);    // pre-swizzled source chunk
  const unsigned short* Kg = qkv + C_DIM + kvh * D_HEAD;
  const unsigned short* Vg = Vt + (size_t)(kvh * 64) * T_SEQ;

  bf16x8 qf[2][2];
  for (int qs = 0; qs < 2; ++qs)
    for (int dc = 0; dc < 2; ++dc)
      qf[qs][dc] = load8(&qkv[(size_t)(q0 + qs * 16 + lrow) * NQKV + h * D_HEAD + dc * 32 + g * 8]);

  f32x4 o[2][4] = {};                 // [qs][dt]: rows=d (4g+r), cols=q (lrow)
  float l_[2] = {0.f, 0.f};           // lane-local partial (reduced at epilogue)
  const int swz = (lrow & 7);         // K read-side chunk swizzle
  const int vswz = (lrow & 3);        // V read-side chunk swizzle

  {                                   // prologue: stage tile t0
    const int k00 = t0 * 32;
    GLOAD_LDS16(Kg + (size_t)(k00 + wave * 8 + ksrow) * NQKV + kchunk * 8,
                &kbuf[0][(wave * 8) * 64 + lane * 8]);
    GLOAD_LDS16(Vg + (size_t)(wave * 16 + vsrow) * T_SEQ + k00 + vchunk * 8,
                &vbuf[0][(wave * 16) * 32 + lane * 8]);
  }
  __syncthreads();

  for (int t = t0; t < t1; ++t) {
    const int cur = (t - t0) & 1;
    const int k0 = t * 32;
    if (t + 1 < t1) {                 // prefetch next tile
      const int k0n = k0 + 32;
      GLOAD_LDS16(Kg + (size_t)(k0n + wave * 8 + ksrow) * NQKV + kchunk * 8,
                  &kbuf[cur ^ 1][(wave * 8) * 64 + lane * 8]);
      GLOAD_LDS16(Vg + (size_t)(wave * 16 + vsrow) * T_SEQ + k0n + vchunk * 8,
                  &vbuf[cur ^ 1][(wave * 16) * 32 + lane * 8]);
    }

    if (k0 <= q0 + 31) {              // causal: skip fully-masked tiles
      const bool maskt = (k0 + 31 > q0);

      // ---- QK^T (swapped): s[kt][qs] rows = keys (16kt+4g+r), cols = q
      f32x4 s[2][2] = {};
      __builtin_amdgcn_s_setprio(1);
      for (int kt = 0; kt < 2; ++kt) {
        const unsigned short* krow = &kbuf[cur][(kt * 16 + lrow) * 64];
        const bf16x8 kf0 = load8(krow + ((0 * 4 + g) ^ swz) * 8);
        const bf16x8 kf1 = load8(krow + ((1 * 4 + g) ^ swz) * 8);
        for (int qs = 0; qs < 2; ++qs) {
          s[kt][qs] = mfma16(kf0, qf[qs][0], s[kt][qs]);
          s[kt][qs] = mfma16(kf1, qf[qs][1], s[kt][qs]);
        }
      }
      __builtin_amdgcn_s_setprio(0);

      // bf16-faithful rounding (q pre-scaled by 0.125*log2e) + causal mask,
      // P = exp2(s); l accumulated lane-local.
      for (int qs = 0; qs < 2; ++qs) {
        float rs = 0.f;
        for (int kt = 0; kt < 2; ++kt)
          for (int r = 0; r < 4; ++r) {
            float v = (float)(__bf16)(s[kt][qs][r]);
            if (maskt) {
              const int ka = k0 + kt * 16 + 4 * g + r;
              const int qa = q0 + qs * 16 + lrow;
              v = (ka <= qa) ? v : -INFINITY;
            }
            const float p = __builtin_amdgcn_exp2f(v);   // -inf -> 0
            s[kt][qs][r] = p;
            rs += p;
          }
        l_[qs] += rs;
      }

      // ---- P -> per-wave LDS (transpose to [q][32k])
      for (int qs = 0; qs < 2; ++qs)
        for (int kt = 0; kt < 2; ++kt) {
          union { __bf16 h4[4]; unsigned long long u; } w;
          for (int r = 0; r < 4; ++r) w.h4[r] = (__bf16)(s[kt][qs][r]);
          *reinterpret_cast<unsigned long long*>(
              &plds[wave][qs][lrow][kt * 16 + 4 * g]) = w.u;
        }
      asm volatile("s_waitcnt lgkmcnt(0)" ::: "memory");

      // ---- PV (swapped): o[qs][dt] += mfma(V_frag, P_frag)
      __builtin_amdgcn_s_setprio(1);
      {
        const bf16x8 pf0 = load8(&plds[wave][0][lrow][g * 8]);
        const bf16x8 pf1 = load8(&plds[wave][1][lrow][g * 8]);
        for (int dt = 0; dt < 4; ++dt) {
          const bf16x8 vf =
              load8(&vbuf[cur][(dt * 16 + lrow) * 32 + (g ^ vswz) * 8]);
          o[0][dt] = mfma16(vf, pf0, o[0][dt]);
          o[1][dt] = mfma16(vf, pf1, o[1][dt]);
        }
      }
      __builtin_amdgcn_s_setprio(0);
    }
    __syncthreads();   // drains vmcnt (prefetch) + protects buffers
  }

  // ---- epilogue: reduce l across lanes; per-qs transpose via plds; store
  for (int qs = 0; qs < 2; ++qs) {
    float lv = l_[qs];
    lv += __shfl_xor(lv, 16);
    lv += __shfl_xor(lv, 32);
    l_[qs] = lv;
  }
  unsigned short* ol = &plds[wave][0][0][0];        // view as [16][72] per pass
  for (int qs = 0; qs < 2; ++qs) {
    const float inv = 1.f / l_[qs];
    for (int dt = 0; dt < 4; ++dt) {
      union { __bf16 h4[4]; unsigned long long u; } w;
      for (int r = 0; r < 4; ++r) w.h4[r] = (__bf16)(o[qs][dt][r] * inv);
      *reinterpret_cast<unsigned long long*>(
          &ol[lrow * 72 + dt * 16 + 4 * g]) = w.u;
    }
    asm volatile("s_waitcnt lgkmcnt(0)" ::: "memory");
    for (int rr = 0; rr < 2; ++rr) {
      const int row = rr * 8 + (lane >> 3);
      const int cs = (lane & 7) * 8;
      const bf16x8 v = load8(&ol[row * 72 + cs]);
      *reinterpret_cast<bf16x8*>(
          &po[(size_t)slot * 8192 + (wave * 32 + qs * 16 + row) * 64 + cs]) = v;
    }
    asm volatile("s_waitcnt lgkmcnt(0)" ::: "memory");
  }
  if (g == 0)
    for (int qs = 0; qs < 2; ++qs)
      pml[slot * 128 + wave * 32 + qs * 16 + lrow] = make_float2(0.f, l_[qs]);
}

// ---------------------------------------------------------------------------
// Combine: merge <=4 segment partials per (head, 128-q block) -> aout bf16
// ---------------------------------------------------------------------------
__global__ __launch_bounds__(256) void attn_combine_kernel(
    const unsigned short* __restrict__ po, const float2* __restrict__ pml,
    unsigned short* __restrict__ aout) {
  const int qg = blockIdx.x, h = blockIdx.y;
  const int nseg = (2 * qg + 9) / 8;
  const int tid = threadIdx.x;
  const int row = tid >> 1, c0 = (tid & 1) * 32;
  float L = 0.f, w[4];
  for (int s = 0; s < nseg; ++s) {
    const int slot = h * 40 + kQGF[qg][s];
    w[s] = pml[slot * 128 + row].y;     // m==0 everywhere -> weight = l
    L += w[s];
  }
  float acc[32] = {};
  for (int s = 0; s < nseg; ++s) {
    const int slot = h * 40 + kQGF[qg][s];
    const unsigned short* p = &po[(size_t)slot * 8192 + row * 64 + c0];
    for (int j = 0; j < 4; ++j) {
      const bf16x8 v = load8(p + j * 8);
      for (int e = 0; e < 8; ++e) acc[j * 8 + e] += w[s] * (float)v[e];
    }
  }
  const float invL = 1.f / L;
  for (int j = 0; j < 4; ++j) {
    __bf16 ov[8];
    for (int e = 0; e < 8; ++e) ov[e] = (__bf16)(acc[j * 8 + e] * invL);
    *reinterpret_cast<bf16x8*>(
        &aout[(size_t)(qg * 128 + row) * C_DIM + h * D_HEAD + c0 + j * 8]) =
        *reinterpret_cast<const bf16x8*>(ov);
  }
}

// ---------------------------------------------------------------------------
// GEMM3: out = attn_out(bf16) @ Wo. BM=64, BN=128 -> 512 blocks (grid fill).
// 2x2 waves, each 32x64. BK=64, XOR swizzle, bijective XCD swizzle.
// ---------------------------------------------------------------------------
__global__ __launch_bounds__(256, 2) void gemm3_kernel(
    const unsigned short* __restrict__ A, const unsigned short* __restrict__ BT,
    float* __restrict__ out) {
  __shared__ unsigned short As[64 * 64], Bs[128 * 64];
  const int tid = threadIdx.x;
  const int orig = (int)blockIdx.y * 16 + (int)blockIdx.x;   // 512 blocks
  const int wgid = (orig & 7) * 64 + (orig >> 3);            // bijective XCD swz
  const int n0 = (wgid % 16) * 128, m0 = (wgid / 16) * 64;
  const int lane = tid & 63, wave = tid >> 6;
  const int wm = wave >> 1, wn = wave & 1;
  const int lrow = lane & 15, g = lane >> 4;
  const int srow8 = lane >> 3, pchunk = lane & 7;
  const int swz = lrow & 7;
  f32x4 acc[2][4] = {};
  for (int kb = 0; kb < C_DIM; kb += 64) {
    __syncthreads();
    for (int p = 0; p < 2; ++p) {
      const int row = (p * 4 + wave) * 8 + srow8;
      const int gcol = (pchunk ^ srow8) * 8;
      GLOAD_LDS16(&A[(size_t)(m0 + row) * C_DIM + kb + gcol],
                  &As[row * 64 + pchunk * 8]);
    }
    for (int p = 0; p < 4; ++p) {
      const int row = (p * 4 + wave) * 8 + srow8;
      const int gcol = (pchunk ^ srow8) * 8;
      GLOAD_LDS16(&BT[(size_t)(n0 + row) * C_DIM + kb + gcol],
                  &Bs[row * 64 + pchunk * 8]);
    }
    __syncthreads();
    for (int kk = 0; kk < 2; ++kk) {
      bf16x8 af[2], bfr[4];
      const int cc = ((kk * 4 + g) ^ swz) * 8;
      for (int i = 0; i < 2; ++i)
        af[i] = load8(&As[(wm * 32 + i * 16 + lrow) * 64 + cc]);
      for (int i = 0; i < 4; ++i)
        bfr[i] = load8(&Bs[(wn * 64 + i * 16 + lrow) * 64 + cc]);
      for (int mi = 0; mi < 2; ++mi)
        for (int ni = 0; ni < 4; ++ni)
          acc[mi][ni] = mfma16(af[mi], bfr[ni], acc[mi][ni]);
    }
  }
  for (int mi = 0; mi < 2; ++mi)
    for (int ni = 0; ni < 4; ++ni)
      for (int r = 0; r < 4; ++r)
        out[(size_t)(m0 + wm * 32 + mi * 16 + g * 4 + r) * C_DIM +
            n0 + wn * 64 + ni * 16 + lrow] = acc[mi][ni][r];
}

// ---------------------------------------------------------------------------
extern "C" void kernel_launch(void* const* d_in, const int* in_sizes, int n_in,
                              void* d_out, int out_size, void* d_ws, size_t ws_size,
                              hipStream_t stream) {
  (void)in_sizes; (void)n_in; (void)out_size; (void)ws_size;
  const float* x    = (const float*)d_in[0];
  const float* cosb = (const float*)d_in[1];
  const float* sinb = (const float*)d_in[2];
  const float* Wqkv = (const float*)d_in[3];
  const float* Wo   = (const float*)d_in[4];
  float* out = (float*)d_out;

  unsigned short* WqkvT_hi = (unsigned short*)d_ws;                       // [3072][2048]
  unsigned short* WoT      = WqkvT_hi + (size_t)NQKV * C_DIM;             // [2048][2048]
  unsigned short* qkv      = WoT + (size_t)C_DIM * C_DIM;                 // [2048][3072]
  unsigned short* Vt       = qkv + (size_t)T_SEQ * NQKV;                  // [512][2048]
  unsigned short* aout     = Vt + (size_t)KVH_ * D_HEAD * T_SEQ;          // [2048][2048]
  unsigned short* Xh       = aout + (size_t)T_SEQ * C_DIM;                // [2048][2048]
  // Partials (attn runs after gemm1, so Xh and WqkvT_hi are dead then):
  unsigned short* po  = Xh;              // 1280 x 128 x 64 bf16 = 21.0 MB
  float2*         pml = (float2*)d_ws;   // 1280 x 128 float2 = 1.3 MB

  cast_x_kernel<<<(T_SEQ * C_DIM) / (256 * 8), 256, 0, stream>>>(x, Xh);
  transpose_cast_kernel<<<dim3(NQKV / 64, C_DIM / 64), 256, 0, stream>>>(
      Wqkv, WqkvT_hi, C_DIM, NQKV);
  transpose_cast_kernel<<<dim3(C_DIM / 64, C_DIM / 64), 256, 0, stream>>>(
      Wo, WoT, C_DIM, C_DIM);
  gemm1_kernel<<<dim3(24, 32), 256, 0, stream>>>(Xh, WqkvT_hi, cosb, sinb, qkv);
  vt_kernel<<<dim3(T_SEQ / 64, (KVH_ * D_HEAD) / 64), 256, 0, stream>>>(qkv, Vt);
  attn_seg_kernel<<<dim3(40, HQ), 256, 0, stream>>>(qkv, Vt, po, pml);
  attn_combine_kernel<<<dim3(16, HQ), 256, 0, stream>>>(po, pml, aout);
  gemm3_kernel<<<dim3(16, 32), 256, 0, stream>>>(aout, WoT, out);
}

// Round 21
// 131.155 us; speedup vs baseline: 1.0265x; 1.0265x over previous
//
#include <hip/hip_runtime.h>
#include <hip/hip_bf16.h>
#include <cstdint>
#include <cstddef>

// Problem constants (B=1, T=2048, C=2048, H=32, KVH=8, D=64)
#define T_SEQ 2048
#define C_DIM 2048
#define NQKV  3072   // H*D + 2*KVH*D
#define HQ    32
#define KVH_  8
#define D_HEAD 64

using bf16x8 = __attribute__((ext_vector_type(8))) __bf16;
using f32x4  = __attribute__((ext_vector_type(4))) float;

typedef const __attribute__((address_space(1))) void* gas_ptr;
typedef __attribute__((address_space(3))) void* las_ptr;
#define GLOAD_LDS16(g, l) __builtin_amdgcn_global_load_lds((gas_ptr)(g), (las_ptr)(l), 16, 0, 0)

static __device__ __forceinline__ unsigned short f2bf(float f) {
  union { float f; unsigned int u; } v; v.f = f;
  unsigned int u = v.u;
  unsigned int r = u + 0x7fffu + ((u >> 16) & 1u);   // RNE
  return (unsigned short)(r >> 16);
}
static __device__ __forceinline__ float bf2f(unsigned short s) {
  union { unsigned int u; float f; } v; v.u = ((unsigned int)s) << 16;
  return v.f;
}
static __device__ __forceinline__ bf16x8 load8(const unsigned short* p) {
  return *reinterpret_cast<const bf16x8*>(p);
}
static __device__ __forceinline__ f32x4 mfma16(bf16x8 a, bf16x8 b, f32x4 c) {
  return __builtin_amdgcn_mfma_f32_16x16x32_bf16(a, b, c, 0, 0, 0);
}

// Heavy-first static schedule for attn split-K blocks (40 per head):
// f -> (qg, seg) sorted by tile count desc (27x8-tile, 4x6, 4x4, 5x2).
static __device__ const unsigned char kF2QG[40] = {
    15, 15, 15, 15, 14, 14, 14, 13, 13, 13, 12, 12, 12, 11, 11,
    10, 10, 9, 9, 8, 8, 7, 7, 6, 5, 4, 3,
    14, 11, 6, 2, 13, 10, 5, 1, 12, 9, 8, 4, 0};
static __device__ const unsigned char kF2SEG[40] = {
    0, 1, 2, 3, 0, 1, 2, 0, 1, 2, 0, 1, 2, 0, 1,
    0, 1, 0, 1, 0, 1, 0, 1, 0, 0, 0, 0,
    3, 2, 1, 0, 3, 2, 1, 0, 3, 2, 2, 1, 0};
// Inverse: qg -> f index of each of its segments.
static __device__ const unsigned char kQGF[16][4] = {
    {39, 0, 0, 0}, {34, 0, 0, 0}, {30, 0, 0, 0}, {26, 0, 0, 0},
    {25, 38, 0, 0}, {24, 33, 0, 0}, {23, 29, 0, 0}, {21, 22, 0, 0},
    {19, 20, 37, 0}, {17, 18, 36, 0}, {15, 16, 32, 0}, {13, 14, 28, 0},
    {10, 11, 12, 35}, {7, 8, 9, 31}, {4, 5, 6, 27}, {0, 1, 2, 3}};

// ---------------------------------------------------------------------------
// cast_x: x f32 -> bf16 row-major, 8 elems/thread
// ---------------------------------------------------------------------------
__global__ __launch_bounds__(256) void cast_x_kernel(
    const float* __restrict__ x, unsigned short* __restrict__ xh) {
  const int i = (blockIdx.x * 256 + threadIdx.x) * 8;
  const float4 a = *reinterpret_cast<const float4*>(x + i);
  const float4 b = *reinterpret_cast<const float4*>(x + i + 4);
  ushort h[8];
  h[0] = f2bf(a.x); h[1] = f2bf(a.y); h[2] = f2bf(a.z); h[3] = f2bf(a.w);
  h[4] = f2bf(b.x); h[5] = f2bf(b.y); h[6] = f2bf(b.z); h[7] = f2bf(b.w);
  *reinterpret_cast<uint4*>(xh + i) = *reinterpret_cast<const uint4*>(h);
}

// ---------------------------------------------------------------------------
// Transpose + f32->bf16 cast: src[R][C] -> dst[C][R]
// ---------------------------------------------------------------------------
__global__ __launch_bounds__(256) void transpose_cast_kernel(
    const float* __restrict__ src, unsigned short* __restrict__ dhi, int R, int C) {
  __shared__ float tile[64][65];
  const int r0 = blockIdx.y * 64, c0 = blockIdx.x * 64;
  const int tid = threadIdx.x;
  const int lr = tid >> 4, lc = (tid & 15) * 4;
  for (int i = 0; i < 4; ++i) {
    const int row = lr + i * 16;
    const float4 v = *reinterpret_cast<const float4*>(&src[(size_t)(r0 + row) * C + c0 + lc]);
    tile[row][lc + 0] = v.x; tile[row][lc + 1] = v.y;
    tile[row][lc + 2] = v.z; tile[row][lc + 3] = v.w;
  }
  __syncthreads();
  for (int i = 0; i < 4; ++i) {
    const int n = lr + i * 16;
    ushort4 h;
    h.x = f2bf(tile[lc + 0][n]); h.y = f2bf(tile[lc + 1][n]);
    h.z = f2bf(tile[lc + 2][n]); h.w = f2bf(tile[lc + 3][n]);
    *reinterpret_cast<ushort4*>(&dhi[(size_t)(c0 + n) * R + r0 + lc]) = h;
  }
}

// ---------------------------------------------------------------------------
// GEMM1: qkv = bf16(x) @ bf16(Wqkv). BM=64, BN=128 -> 768 blocks (grid fill).
// 2x2 waves, each 32x64 (full head per wave for RoPE). BK=64, XOR swizzle.
// Epilogue: RoPE; q pre-scaled by 0.125*log2(e) (exp2-fold).
// ---------------------------------------------------------------------------
__global__ __launch_bounds__(256, 2) void gemm1_kernel(
    const unsigned short* __restrict__ Xh, const unsigned short* __restrict__ BTh,
    const float* __restrict__ cosb, const float* __restrict__ sinb,
    unsigned short* __restrict__ qkv) {
  __shared__ unsigned short Ah[64 * 64], Bh[128 * 64];
  const int tid = threadIdx.x;
  const int orig = (int)blockIdx.y * 24 + (int)blockIdx.x;   // 768 blocks
  const int wgid = (orig & 7) * 96 + (orig >> 3);            // bijective XCD swz
  const int n0 = (wgid % 24) * 128, m0 = (wgid / 24) * 64;
  const int lane = tid & 63, wave = tid >> 6;
  const int wm = wave >> 1, wn = wave & 1;      // 2x2 waves, 32x64 per wave
  const int lrow = lane & 15, g = lane >> 4;
  const int srow8 = lane >> 3, pchunk = lane & 7;
  const int swz = lrow & 7;
  f32x4 acc[2][4] = {};
  for (int kb = 0; kb < C_DIM; kb += 64) {
    __syncthreads();
    for (int p = 0; p < 2; ++p) {               // A: 64 rows
      const int row = (p * 4 + wave) * 8 + srow8;
      const int gcol = (pchunk ^ srow8) * 8;
      GLOAD_LDS16(&Xh[(size_t)(m0 + row) * C_DIM + kb + gcol],
                  &Ah[row * 64 + pchunk * 8]);
    }
    for (int p = 0; p < 4; ++p) {               // B: 128 rows
      const int row = (p * 4 + wave) * 8 + srow8;
      const int gcol = (pchunk ^ srow8) * 8;
      GLOAD_LDS16(&BTh[(size_t)(n0 + row) * C_DIM + kb + gcol],
                  &Bh[row * 64 + pchunk * 8]);
    }
    __syncthreads();
    for (int kk = 0; kk < 2; ++kk) {
      bf16x8 ah[2], bh[4];
      const int cc = ((kk * 4 + g) ^ swz) * 8;
      for (int i = 0; i < 2; ++i)
        ah[i] = load8(&Ah[(wm * 32 + i * 16 + lrow) * 64 + cc]);
      for (int i = 0; i < 4; ++i)
        bh[i] = load8(&Bh[(wn * 64 + i * 16 + lrow) * 64 + cc]);
      for (int mi = 0; mi < 2; ++mi)
        for (int ni = 0; ni < 4; ++ni)
          acc[mi][ni] = mfma16(ah[mi], bh[ni], acc[mi][ni]);
    }
  }
  const int colbase = n0 + wn * 64;                 // 64-aligned => one head
  const bool isv = colbase >= (C_DIM + KVH_ * D_HEAD);
  // q scale folds softmax's 1/8 AND log2(e) so attn uses raw v_exp (base 2).
  const float qsc = (colbase < C_DIM) ? 0.18033688011112042f : 1.0f;
  for (int mi = 0; mi < 2; ++mi) {
    for (int r = 0; r < 4; ++r) {
      const int trow = m0 + wm * 32 + mi * 16 + g * 4 + r;
      if (!isv) {
        for (int ni = 0; ni < 2; ++ni) {
          const int dh = ni * 16 + lrow;            // 0..31
          const float c = cosb[trow * 32 + dh];
          const float s = sinb[trow * 32 + dh];
          const float a = bf2f(f2bf(acc[mi][ni][r]));       // ref: bf16 then f32 rope
          const float b = bf2f(f2bf(acc[mi][ni + 2][r]));
          qkv[(size_t)trow * NQKV + colbase + dh]      = f2bf((a * c - b * s) * qsc);
          qkv[(size_t)trow * NQKV + colbase + dh + 32] = f2bf((a * s + b * c) * qsc);
        }
      } else {
        for (int ni = 0; ni < 4; ++ni)
          qkv[(size_t)trow * NQKV + colbase + ni * 16 + lrow] = f2bf(acc[mi][ni][r]);
      }
    }
  }
}

// ---------------------------------------------------------------------------
// V transpose: Vt[kvh*64+d][t] = qkv[t][2560 + kvh*64 + d]
// ---------------------------------------------------------------------------
__global__ __launch_bounds__(256) void vt_kernel(const unsigned short* __restrict__ qkv,
                                                 unsigned short* __restrict__ vt) {
  __shared__ unsigned short tile[64][72];
  const int t0 = blockIdx.x * 64, j0 = blockIdx.y * 64;
  const int tid = threadIdx.x;
  const int lr = tid >> 4, lc = (tid & 15) * 4;
  for (int i = 0; i < 4; ++i) {
    const int row = lr + i * 16;
    const ushort4 v = *reinterpret_cast<const ushort4*>(
        &qkv[(size_t)(t0 + row) * NQKV + (C_DIM + KVH_ * D_HEAD) + j0 + lc]);
    *reinterpret_cast<ushort4*>(&tile[row][lc]) = v;
  }
  __syncthreads();
  for (int i = 0; i < 4; ++i) {
    const int j = lr + i * 16;
    ushort4 v;
    v.x = tile[lc + 0][j]; v.y = tile[lc + 1][j];
    v.z = tile[lc + 2][j]; v.w = tile[lc + 3][j];
    *reinterpret_cast<ushort4*>(&vt[(size_t)(j0 + j) * T_SEQ + t0 + lc]) = v;
  }
}

// ---------------------------------------------------------------------------
// Flash attention, split-K (round-19 structure, 45.7us known-good):
// K,V dbuf LDS (KVBLK=64), fixed-reference softmax P=exp2(s), heavy-first
// schedule, deferred l-reduce. Round-21: drop the score bf16 round-trip
// (2 cvt VALU/element off the binding VALU pipe; deviation = reference's own
// rounding noise, averaged out by softmax).
// ---------------------------------------------------------------------------
__global__ __launch_bounds__(256, 3) void attn_seg_kernel(
    const unsigned short* __restrict__ qkv, const unsigned short* __restrict__ Vt,
    unsigned short* __restrict__ po, float2* __restrict__ pml) {
  __shared__ unsigned short kbuf[2][64 * 64];     // [buf][row k][d] (chunk-swz)
  __shared__ unsigned short vbuf[2][64 * 64];     // [buf][row d][t] (chunk-swz)
  __shared__ unsigned short plds[4][2][16][72];   // [wave][qs][q-row][64k + pad]
  const int f = blockIdx.x, h = blockIdx.y;
  const int qg = kF2QG[f];
  const int seg = kF2SEG[f];
  const int slot = h * 40 + f;
  const int tid = threadIdx.x;
  const int wave = tid >> 6, lane = tid & 63;
  const int kvh = h >> 2;
  const int q0b = qg * 128;
  const int q0 = q0b + wave * 32;
  const int lrow = lane & 15, g = lane >> 4;

  const int t0 = seg * 8;
  const int t1 = min(t0 + 8, 2 * qg + 2);         // tiles [t0, t1)

  const int srow = lane >> 3;                     // row within 8-row group
  const int schunk = (lane & 7) ^ srow;           // pre-swizzled source chunk
  const unsigned short* Kg = qkv + C_DIM + kvh * D_HEAD;

  bf16x8 qf[2][2];
  for (int qs = 0; qs < 2; ++qs)
    for (int dc = 0; dc < 2; ++dc)
      qf[qs][dc] = load8(&qkv[(size_t)(q0 + qs * 16 + lrow) * NQKV + h * D_HEAD + dc * 32 + g * 8]);

  f32x4 o[2][4] = {};                 // [qs][dt]: rows=d (4g+r), cols=q (lrow)
  float l_[2] = {0.f, 0.f};           // lane-local partial (reduced at epilogue)
  const int swz = (lrow & 7);         // read-side chunk swizzle

  {
    const int k00 = t0 * 64;
    for (int j = 0; j < 2; ++j) {
      const int r0 = wave * 16 + j * 8;
      GLOAD_LDS16(Kg + (size_t)(k00 + r0 + srow) * NQKV + schunk * 8,
                  &kbuf[0][r0 * 64 + lane * 8]);
      GLOAD_LDS16(Vt + (size_t)(kvh * 64 + r0 + srow) * T_SEQ + k00 + schunk * 8,
                  &vbuf[0][r0 * 64 + lane * 8]);
    }
  }
  __syncthreads();

  for (int t = t0; t < t1; ++t) {
    const int cur = (t - t0) & 1;
    const int k0 = t * 64;
    if (t + 1 < t1) {
      const int k0n = k0 + 64;
      for (int j = 0; j < 2; ++j) {
        const int r0 = wave * 16 + j * 8;
        GLOAD_LDS16(Kg + (size_t)(k0n + r0 + srow) * NQKV + schunk * 8,
                    &kbuf[cur ^ 1][r0 * 64 + lane * 8]);
        GLOAD_LDS16(Vt + (size_t)(kvh * 64 + r0 + srow) * T_SEQ + k0n + schunk * 8,
                    &vbuf[cur ^ 1][r0 * 64 + lane * 8]);
      }
    }

    if (k0 <= q0 + 31) {              // causal: skip fully-masked tiles
      const bool maskt = (k0 + 63 > q0);

      f32x4 s[4][2] = {};
      __builtin_amdgcn_s_setprio(1);
      for (int kt = 0; kt < 4; ++kt) {
        const unsigned short* krow = &kbuf[cur][(kt * 16 + lrow) * 64];
        const bf16x8 kf0 = load8(krow + ((0 * 4 + g) ^ swz) * 8);
        const bf16x8 kf1 = load8(krow + ((1 * 4 + g) ^ swz) * 8);
        for (int qs = 0; qs < 2; ++qs) {
          s[kt][qs] = mfma16(kf0, qf[qs][0], s[kt][qs]);
          s[kt][qs] = mfma16(kf1, qf[qs][1], s[kt][qs]);
        }
      }
      __builtin_amdgcn_s_setprio(0);

      // causal mask + P = exp2(s) (q pre-scaled by 0.125*log2e);
      // score bf16-round dropped (r21): deviation = ref's own rounding noise.
      for (int qs = 0; qs < 2; ++qs) {
        float rs = 0.f;
        for (int kt = 0; kt < 4; ++kt)
          for (int r = 0; r < 4; ++r) {
            float v = s[kt][qs][r];
            if (maskt) {
              const int ka = k0 + kt * 16 + 4 * g + r;
              const int qa = q0 + qs * 16 + lrow;
              v = (ka <= qa) ? v : -INFINITY;
            }
            const float p = __builtin_amdgcn_exp2f(v);   // -inf -> 0
            s[kt][qs][r] = p;
            rs += p;
          }
        l_[qs] += rs;
      }

      // ---- P -> per-wave LDS (transpose to [q][k])
      for (int qs = 0; qs < 2; ++qs)
        for (int kt = 0; kt < 4; ++kt) {
          union { __bf16 h4[4]; unsigned long long u; } w;
          for (int r = 0; r < 4; ++r) w.h4[r] = (__bf16)(s[kt][qs][r]);
          *reinterpret_cast<unsigned long long*>(
              &plds[wave][qs][lrow][kt * 16 + 4 * g]) = w.u;
        }
      asm volatile("s_waitcnt lgkmcnt(0)" ::: "memory");

      // ---- PV (swapped): o[qs][dt] += mfma(V_frag, P_frag)
      __builtin_amdgcn_s_setprio(1);
      for (int kc = 0; kc < 2; ++kc) {
        const bf16x8 pf0 = load8(&plds[wave][0][lrow][kc * 32 + g * 8]);
        const bf16x8 pf1 = load8(&plds[wave][1][lrow][kc * 32 + g * 8]);
        for (int dt = 0; dt < 4; ++dt) {
          const bf16x8 vf =
              load8(&vbuf[cur][(dt * 16 + lrow) * 64 + ((kc * 4 + g) ^ swz) * 8]);
          o[0][dt] = mfma16(vf, pf0, o[0][dt]);
          o[1][dt] = mfma16(vf, pf1, o[1][dt]);
        }
      }
      __builtin_amdgcn_s_setprio(0);
    }
    __syncthreads();   // drains vmcnt (prefetch) + protects buffers
  }

  // ---- epilogue: reduce l across lanes, write partials o/l + (m=0, l)
  for (int qs = 0; qs < 2; ++qs) {
    float lv = l_[qs];
    lv += __shfl_xor(lv, 16);
    lv += __shfl_xor(lv, 32);
    l_[qs] = lv;
  }
  unsigned short* ol = &plds[wave][0][0][0];        // view as [32][72]
  for (int qs = 0; qs < 2; ++qs) {
    const float inv = 1.f / l_[qs];
    for (int dt = 0; dt < 4; ++dt) {
      union { __bf16 h4[4]; unsigned long long u; } w;
      for (int r = 0; r < 4; ++r) w.h4[r] = (__bf16)(o[qs][dt][r] * inv);
      *reinterpret_cast<unsigned long long*>(
          &ol[(qs * 16 + lrow) * 72 + dt * 16 + 4 * g]) = w.u;
    }
  }
  asm volatile("s_waitcnt lgkmcnt(0)" ::: "memory");
  for (int rr = 0; rr < 4; ++rr) {
    const int row = rr * 8 + (lane >> 3);
    const int cs = (lane & 7) * 8;
    const bf16x8 v = load8(&ol[row * 72 + cs]);
    *reinterpret_cast<bf16x8*>(
        &po[(size_t)slot * 8192 + (wave * 32 + row) * 64 + cs]) = v;
  }
  if (g == 0)
    for (int qs = 0; qs < 2; ++qs)
      pml[slot * 128 + wave * 32 + qs * 16 + lrow] = make_float2(0.f, l_[qs]);
}

// ---------------------------------------------------------------------------
// Combine: merge <=4 segment partials per (head, 128-q block) -> aout bf16
// ---------------------------------------------------------------------------
__global__ __launch_bounds__(256) void attn_combine_kernel(
    const unsigned short* __restrict__ po, const float2* __restrict__ pml,
    unsigned short* __restrict__ aout) {
  const int qg = blockIdx.x, h = blockIdx.y;
  const int nseg = (2 * qg + 9) / 8;
  const int tid = threadIdx.x;
  const int row = tid >> 1, c0 = (tid & 1) * 32;
  float L = 0.f, w[4];
  for (int s = 0; s < nseg; ++s) {
    const int slot = h * 40 + kQGF[qg][s];
    w[s] = pml[slot * 128 + row].y;     // m==0 everywhere -> weight = l
    L += w[s];
  }
  float acc[32] = {};
  for (int s = 0; s < nseg; ++s) {
    const int slot = h * 40 + kQGF[qg][s];
    const unsigned short* p = &po[(size_t)slot * 8192 + row * 64 + c0];
    for (int j = 0; j < 4; ++j) {
      const bf16x8 v = load8(p + j * 8);
      for (int e = 0; e < 8; ++e) acc[j * 8 + e] += w[s] * (float)v[e];
    }
  }
  const float invL = 1.f / L;
  for (int j = 0; j < 4; ++j) {
    __bf16 ov[8];
    for (int e = 0; e < 8; ++e) ov[e] = (__bf16)(acc[j * 8 + e] * invL);
    *reinterpret_cast<bf16x8*>(
        &aout[(size_t)(qg * 128 + row) * C_DIM + h * D_HEAD + c0 + j * 8]) =
        *reinterpret_cast<const bf16x8*>(ov);
  }
}

// ---------------------------------------------------------------------------
// GEMM3: out = attn_out(bf16) @ Wo. BM=64, BN=128 -> 512 blocks (grid fill).
// 2x2 waves, each 32x64. BK=64, XOR swizzle, bijective XCD swizzle.
// ---------------------------------------------------------------------------
__global__ __launch_bounds__(256, 2) void gemm3_kernel(
    const unsigned short* __restrict__ A, const unsigned short* __restrict__ BT,
    float* __restrict__ out) {
  __shared__ unsigned short As[64 * 64], Bs[128 * 64];
  const int tid = threadIdx.x;
  const int orig = (int)blockIdx.y * 16 + (int)blockIdx.x;   // 512 blocks
  const int wgid = (orig & 7) * 64 + (orig >> 3);            // bijective XCD swz
  const int n0 = (wgid % 16) * 128, m0 = (wgid / 16) * 64;
  const int lane = tid & 63, wave = tid >> 6;
  const int wm = wave >> 1, wn = wave & 1;
  const int lrow = lane & 15, g = lane >> 4;
  const int srow8 = lane >> 3, pchunk = lane & 7;
  const int swz = lrow & 7;
  f32x4 acc[2][4] = {};
  for (int kb = 0; kb < C_DIM; kb += 64) {
    __syncthreads();
    for (int p = 0; p < 2; ++p) {
      const int row = (p * 4 + wave) * 8 + srow8;
      const int gcol = (pchunk ^ srow8) * 8;
      GLOAD_LDS16(&A[(size_t)(m0 + row) * C_DIM + kb + gcol],
                  &As[row * 64 + pchunk * 8]);
    }
    for (int p = 0; p < 4; ++p) {
      const int row = (p * 4 + wave) * 8 + srow8;
      const int gcol = (pchunk ^ srow8) * 8;
      GLOAD_LDS16(&BT[(size_t)(n0 + row) * C_DIM + kb + gcol],
                  &Bs[row * 64 + pchunk * 8]);
    }
    __syncthreads();
    for (int kk = 0; kk < 2; ++kk) {
      bf16x8 af[2], bfr[4];
      const int cc = ((kk * 4 + g) ^ swz) * 8;
      for (int i = 0; i < 2; ++i)
        af[i] = load8(&As[(wm * 32 + i * 16 + lrow) * 64 + cc]);
      for (int i = 0; i < 4; ++i)
        bfr[i] = load8(&Bs[(wn * 64 + i * 16 + lrow) * 64 + cc]);
      for (int mi = 0; mi < 2; ++mi)
        for (int ni = 0; ni < 4; ++ni)
          acc[mi][ni] = mfma16(af[mi], bfr[ni], acc[mi][ni]);
    }
  }
  for (int mi = 0; mi < 2; ++mi)
    for (int ni = 0; ni < 4; ++ni)
      for (int r = 0; r < 4; ++r)
        out[(size_t)(m0 + wm * 32 + mi * 16 + g * 4 + r) * C_DIM +
            n0 + wn * 64 + ni * 16 + lrow] = acc[mi][ni][r];
}

// ---------------------------------------------------------------------------
extern "C" void kernel_launch(void* const* d_in, const int* in_sizes, int n_in,
                              void* d_out, int out_size, void* d_ws, size_t ws_size,
                              hipStream_t stream) {
  (void)in_sizes; (void)n_in; (void)out_size; (void)ws_size;
  const float* x    = (const float*)d_in[0];
  const float* cosb = (const float*)d_in[1];
  const float* sinb = (const float*)d_in[2];
  const float* Wqkv = (const float*)d_in[3];
  const float* Wo   = (const float*)d_in[4];
  float* out = (float*)d_out;

  unsigned short* WqkvT_hi = (unsigned short*)d_ws;                       // [3072][2048]
  unsigned short* WoT      = WqkvT_hi + (size_t)NQKV * C_DIM;             // [2048][2048]
  unsigned short* qkv      = WoT + (size_t)C_DIM * C_DIM;                 // [2048][3072]
  unsigned short* Vt       = qkv + (size_t)T_SEQ * NQKV;                  // [512][2048]
  unsigned short* aout     = Vt + (size_t)KVH_ * D_HEAD * T_SEQ;          // [2048][2048]
  unsigned short* Xh       = aout + (size_t)T_SEQ * C_DIM;                // [2048][2048]
  // Partials (attn runs after gemm1, so Xh and WqkvT_hi are dead then):
  unsigned short* po  = Xh;              // 1280 x 128 x 64 bf16 = 21.0 MB
  float2*         pml = (float2*)d_ws;   // 1280 x 128 float2 = 1.3 MB

  cast_x_kernel<<<(T_SEQ * C_DIM) / (256 * 8), 256, 0, stream>>>(x, Xh);
  transpose_cast_kernel<<<dim3(NQKV / 64, C_DIM / 64), 256, 0, stream>>>(
      Wqkv, WqkvT_hi, C_DIM, NQKV);
  transpose_cast_kernel<<<dim3(C_DIM / 64, C_DIM / 64), 256, 0, stream>>>(
      Wo, WoT, C_DIM, C_DIM);
  gemm1_kernel<<<dim3(24, 32), 256, 0, stream>>>(Xh, WqkvT_hi, cosb, sinb, qkv);
  vt_kernel<<<dim3(T_SEQ / 64, (KVH_ * D_HEAD) / 64), 256, 0, stream>>>(qkv, Vt);
  attn_seg_kernel<<<dim3(40, HQ), 256, 0, stream>>>(qkv, Vt, po, pml);
  attn_combine_kernel<<<dim3(16, HQ), 256, 0, stream>>>(po, pml, aout);
  gemm3_kernel<<<dim3(16, 32), 256, 0, stream>>>(aout, WoT, out);
}

// Round 22
// 126.729 us; speedup vs baseline: 1.0624x; 1.0349x over previous
//
#include <hip/hip_runtime.h>
#include <hip/hip_bf16.h>
#include <cstdint>
#include <cstddef>

// Problem constants (B=1, T=2048, C=2048, H=32, KVH=8, D=64)
#define T_SEQ 2048
#define C_DIM 2048
#define NQKV  3072   // H*D + 2*KVH*D
#define HQ    32
#define KVH_  8
#define D_HEAD 64

using bf16x8 = __attribute__((ext_vector_type(8))) __bf16;
using f32x4  = __attribute__((ext_vector_type(4))) float;

typedef const __attribute__((address_space(1))) void* gas_ptr;
typedef __attribute__((address_space(3))) void* las_ptr;
#define GLOAD_LDS16(g, l) __builtin_amdgcn_global_load_lds((gas_ptr)(g), (las_ptr)(l), 16, 0, 0)

static __device__ __forceinline__ unsigned short f2bf(float f) {
  union { float f; unsigned int u; } v; v.f = f;
  unsigned int u = v.u;
  unsigned int r = u + 0x7fffu + ((u >> 16) & 1u);   // RNE
  return (unsigned short)(r >> 16);
}
static __device__ __forceinline__ float bf2f(unsigned short s) {
  union { unsigned int u; float f; } v; v.u = ((unsigned int)s) << 16;
  return v.f;
}
static __device__ __forceinline__ bf16x8 load8(const unsigned short* p) {
  return *reinterpret_cast<const bf16x8*>(p);
}
static __device__ __forceinline__ f32x4 mfma16(bf16x8 a, bf16x8 b, f32x4 c) {
  return __builtin_amdgcn_mfma_f32_16x16x32_bf16(a, b, c, 0, 0, 0);
}

// Heavy-first static schedule for attn split-K blocks (40 per head):
// f -> (qg, seg) sorted by tile count desc (27x8-tile, 4x6, 4x4, 5x2).
static __device__ const unsigned char kF2QG[40] = {
    15, 15, 15, 15, 14, 14, 14, 13, 13, 13, 12, 12, 12, 11, 11,
    10, 10, 9, 9, 8, 8, 7, 7, 6, 5, 4, 3,
    14, 11, 6, 2, 13, 10, 5, 1, 12, 9, 8, 4, 0};
static __device__ const unsigned char kF2SEG[40] = {
    0, 1, 2, 3, 0, 1, 2, 0, 1, 2, 0, 1, 2, 0, 1,
    0, 1, 0, 1, 0, 1, 0, 1, 0, 0, 0, 0,
    3, 2, 1, 0, 3, 2, 1, 0, 3, 2, 2, 1, 0};
// Inverse: qg -> f index of each of its segments.
static __device__ const unsigned char kQGF[16][4] = {
    {39, 0, 0, 0}, {34, 0, 0, 0}, {30, 0, 0, 0}, {26, 0, 0, 0},
    {25, 38, 0, 0}, {24, 33, 0, 0}, {23, 29, 0, 0}, {21, 22, 0, 0},
    {19, 20, 37, 0}, {17, 18, 36, 0}, {15, 16, 32, 0}, {13, 14, 28, 0},
    {10, 11, 12, 35}, {7, 8, 9, 31}, {4, 5, 6, 27}, {0, 1, 2, 3}};

// ---------------------------------------------------------------------------
// cast_x: x f32 -> bf16 row-major, 8 elems/thread
// ---------------------------------------------------------------------------
__global__ __launch_bounds__(256) void cast_x_kernel(
    const float* __restrict__ x, unsigned short* __restrict__ xh) {
  const int i = (blockIdx.x * 256 + threadIdx.x) * 8;
  const float4 a = *reinterpret_cast<const float4*>(x + i);
  const float4 b = *reinterpret_cast<const float4*>(x + i + 4);
  ushort h[8];
  h[0] = f2bf(a.x); h[1] = f2bf(a.y); h[2] = f2bf(a.z); h[3] = f2bf(a.w);
  h[4] = f2bf(b.x); h[5] = f2bf(b.y); h[6] = f2bf(b.z); h[7] = f2bf(b.w);
  *reinterpret_cast<uint4*>(xh + i) = *reinterpret_cast<const uint4*>(h);
}

// ---------------------------------------------------------------------------
// Transpose + f32->bf16 cast: src[R][C] -> dst[C][R]
// ---------------------------------------------------------------------------
__global__ __launch_bounds__(256) void transpose_cast_kernel(
    const float* __restrict__ src, unsigned short* __restrict__ dhi, int R, int C) {
  __shared__ float tile[64][65];
  const int r0 = blockIdx.y * 64, c0 = blockIdx.x * 64;
  const int tid = threadIdx.x;
  const int lr = tid >> 4, lc = (tid & 15) * 4;
  for (int i = 0; i < 4; ++i) {
    const int row = lr + i * 16;
    const float4 v = *reinterpret_cast<const float4*>(&src[(size_t)(r0 + row) * C + c0 + lc]);
    tile[row][lc + 0] = v.x; tile[row][lc + 1] = v.y;
    tile[row][lc + 2] = v.z; tile[row][lc + 3] = v.w;
  }
  __syncthreads();
  for (int i = 0; i < 4; ++i) {
    const int n = lr + i * 16;
    ushort4 h;
    h.x = f2bf(tile[lc + 0][n]); h.y = f2bf(tile[lc + 1][n]);
    h.z = f2bf(tile[lc + 2][n]); h.w = f2bf(tile[lc + 3][n]);
    *reinterpret_cast<ushort4*>(&dhi[(size_t)(c0 + n) * R + r0 + lc]) = h;
  }
}

// ---------------------------------------------------------------------------
// GEMM1: qkv = bf16(x) @ bf16(Wqkv). BM=64, BN=128 -> 768 blocks (grid fill).
// 2x2 waves, each 32x64 (full head per wave for RoPE). BK=64, XOR swizzle.
// Epilogue: RoPE; q pre-scaled by 0.125*log2(e) (exp2-fold).
// ---------------------------------------------------------------------------
__global__ __launch_bounds__(256, 2) void gemm1_kernel(
    const unsigned short* __restrict__ Xh, const unsigned short* __restrict__ BTh,
    const float* __restrict__ cosb, const float* __restrict__ sinb,
    unsigned short* __restrict__ qkv) {
  __shared__ unsigned short Ah[64 * 64], Bh[128 * 64];
  const int tid = threadIdx.x;
  const int orig = (int)blockIdx.y * 24 + (int)blockIdx.x;   // 768 blocks
  const int wgid = (orig & 7) * 96 + (orig >> 3);            // bijective XCD swz
  const int n0 = (wgid % 24) * 128, m0 = (wgid / 24) * 64;
  const int lane = tid & 63, wave = tid >> 6;
  const int wm = wave >> 1, wn = wave & 1;      // 2x2 waves, 32x64 per wave
  const int lrow = lane & 15, g = lane >> 4;
  const int srow8 = lane >> 3, pchunk = lane & 7;
  const int swz = lrow & 7;
  f32x4 acc[2][4] = {};
  for (int kb = 0; kb < C_DIM; kb += 64) {
    __syncthreads();
    for (int p = 0; p < 2; ++p) {               // A: 64 rows
      const int row = (p * 4 + wave) * 8 + srow8;
      const int gcol = (pchunk ^ srow8) * 8;
      GLOAD_LDS16(&Xh[(size_t)(m0 + row) * C_DIM + kb + gcol],
                  &Ah[row * 64 + pchunk * 8]);
    }
    for (int p = 0; p < 4; ++p) {               // B: 128 rows
      const int row = (p * 4 + wave) * 8 + srow8;
      const int gcol = (pchunk ^ srow8) * 8;
      GLOAD_LDS16(&BTh[(size_t)(n0 + row) * C_DIM + kb + gcol],
                  &Bh[row * 64 + pchunk * 8]);
    }
    __syncthreads();
    for (int kk = 0; kk < 2; ++kk) {
      bf16x8 ah[2], bh[4];
      const int cc = ((kk * 4 + g) ^ swz) * 8;
      for (int i = 0; i < 2; ++i)
        ah[i] = load8(&Ah[(wm * 32 + i * 16 + lrow) * 64 + cc]);
      for (int i = 0; i < 4; ++i)
        bh[i] = load8(&Bh[(wn * 64 + i * 16 + lrow) * 64 + cc]);
      for (int mi = 0; mi < 2; ++mi)
        for (int ni = 0; ni < 4; ++ni)
          acc[mi][ni] = mfma16(ah[mi], bh[ni], acc[mi][ni]);
    }
  }
  const int colbase = n0 + wn * 64;                 // 64-aligned => one head
  const bool isv = colbase >= (C_DIM + KVH_ * D_HEAD);
  // q scale folds softmax's 1/8 AND log2(e) so attn uses raw v_exp (base 2).
  const float qsc = (colbase < C_DIM) ? 0.18033688011112042f : 1.0f;
  for (int mi = 0; mi < 2; ++mi) {
    for (int r = 0; r < 4; ++r) {
      const int trow = m0 + wm * 32 + mi * 16 + g * 4 + r;
      if (!isv) {
        for (int ni = 0; ni < 2; ++ni) {
          const int dh = ni * 16 + lrow;            // 0..31
          const float c = cosb[trow * 32 + dh];
          const float s = sinb[trow * 32 + dh];
          const float a = bf2f(f2bf(acc[mi][ni][r]));       // ref: bf16 then f32 rope
          const float b = bf2f(f2bf(acc[mi][ni + 2][r]));
          qkv[(size_t)trow * NQKV + colbase + dh]      = f2bf((a * c - b * s) * qsc);
          qkv[(size_t)trow * NQKV + colbase + dh + 32] = f2bf((a * s + b * c) * qsc);
        }
      } else {
        for (int ni = 0; ni < 4; ++ni)
          qkv[(size_t)trow * NQKV + colbase + ni * 16 + lrow] = f2bf(acc[mi][ni][r]);
      }
    }
  }
}

// ---------------------------------------------------------------------------
// V transpose: Vt[kvh*64+d][t] = qkv[t][2560 + kvh*64 + d]
// ---------------------------------------------------------------------------
__global__ __launch_bounds__(256) void vt_kernel(const unsigned short* __restrict__ qkv,
                                                 unsigned short* __restrict__ vt) {
  __shared__ unsigned short tile[64][72];
  const int t0 = blockIdx.x * 64, j0 = blockIdx.y * 64;
  const int tid = threadIdx.x;
  const int lr = tid >> 4, lc = (tid & 15) * 4;
  for (int i = 0; i < 4; ++i) {
    const int row = lr + i * 16;
    const ushort4 v = *reinterpret_cast<const ushort4*>(
        &qkv[(size_t)(t0 + row) * NQKV + (C_DIM + KVH_ * D_HEAD) + j0 + lc]);
    *reinterpret_cast<ushort4*>(&tile[row][lc]) = v;
  }
  __syncthreads();
  for (int i = 0; i < 4; ++i) {
    const int j = lr + i * 16;
    ushort4 v;
    v.x = tile[lc + 0][j]; v.y = tile[lc + 1][j];
    v.z = tile[lc + 2][j]; v.w = tile[lc + 3][j];
    *reinterpret_cast<ushort4*>(&vt[(size_t)(j0 + j) * T_SEQ + t0 + lc]) = v;
  }
}

// ---------------------------------------------------------------------------
// Flash attention, split-K (round-21 kernel, 42.6us known-good). Round-22:
// GLOBAL heavy-first dispatch — grid swapped to (HQ, 40) so f is the slow
// dimension: all heads' 8-tile blocks dispatch before any light block.
// ---------------------------------------------------------------------------
__global__ __launch_bounds__(256, 3) void attn_seg_kernel(
    const unsigned short* __restrict__ qkv, const unsigned short* __restrict__ Vt,
    unsigned short* __restrict__ po, float2* __restrict__ pml) {
  __shared__ unsigned short kbuf[2][64 * 64];     // [buf][row k][d] (chunk-swz)
  __shared__ unsigned short vbuf[2][64 * 64];     // [buf][row d][t] (chunk-swz)
  __shared__ unsigned short plds[4][2][16][72];   // [wave][qs][q-row][64k + pad]
  const int h = blockIdx.x, f = blockIdx.y;       // f-major dispatch (heavy 1st)
  const int qg = kF2QG[f];
  const int seg = kF2SEG[f];
  const int slot = h * 40 + f;
  const int tid = threadIdx.x;
  const int wave = tid >> 6, lane = tid & 63;
  const int kvh = h >> 2;
  const int q0b = qg * 128;
  const int q0 = q0b + wave * 32;
  const int lrow = lane & 15, g = lane >> 4;

  const int t0 = seg * 8;
  const int t1 = min(t0 + 8, 2 * qg + 2);         // tiles [t0, t1)

  const int srow = lane >> 3;                     // row within 8-row group
  const int schunk = (lane & 7) ^ srow;           // pre-swizzled source chunk
  const unsigned short* Kg = qkv + C_DIM + kvh * D_HEAD;

  bf16x8 qf[2][2];
  for (int qs = 0; qs < 2; ++qs)
    for (int dc = 0; dc < 2; ++dc)
      qf[qs][dc] = load8(&qkv[(size_t)(q0 + qs * 16 + lrow) * NQKV + h * D_HEAD + dc * 32 + g * 8]);

  f32x4 o[2][4] = {};                 // [qs][dt]: rows=d (4g+r), cols=q (lrow)
  float l_[2] = {0.f, 0.f};           // lane-local partial (reduced at epilogue)
  const int swz = (lrow & 7);         // read-side chunk swizzle

  {
    const int k00 = t0 * 64;
    for (int j = 0; j < 2; ++j) {
      const int r0 = wave * 16 + j * 8;
      GLOAD_LDS16(Kg + (size_t)(k00 + r0 + srow) * NQKV + schunk * 8,
                  &kbuf[0][r0 * 64 + lane * 8]);
      GLOAD_LDS16(Vt + (size_t)(kvh * 64 + r0 + srow) * T_SEQ + k00 + schunk * 8,
                  &vbuf[0][r0 * 64 + lane * 8]);
    }
  }
  __syncthreads();

  for (int t = t0; t < t1; ++t) {
    const int cur = (t - t0) & 1;
    const int k0 = t * 64;
    if (t + 1 < t1) {
      const int k0n = k0 + 64;
      for (int j = 0; j < 2; ++j) {
        const int r0 = wave * 16 + j * 8;
        GLOAD_LDS16(Kg + (size_t)(k0n + r0 + srow) * NQKV + schunk * 8,
                    &kbuf[cur ^ 1][r0 * 64 + lane * 8]);
        GLOAD_LDS16(Vt + (size_t)(kvh * 64 + r0 + srow) * T_SEQ + k0n + schunk * 8,
                    &vbuf[cur ^ 1][r0 * 64 + lane * 8]);
      }
    }

    if (k0 <= q0 + 31) {              // causal: skip fully-masked tiles
      const bool maskt = (k0 + 63 > q0);

      f32x4 s[4][2] = {};
      __builtin_amdgcn_s_setprio(1);
      for (int kt = 0; kt < 4; ++kt) {
        const unsigned short* krow = &kbuf[cur][(kt * 16 + lrow) * 64];
        const bf16x8 kf0 = load8(krow + ((0 * 4 + g) ^ swz) * 8);
        const bf16x8 kf1 = load8(krow + ((1 * 4 + g) ^ swz) * 8);
        for (int qs = 0; qs < 2; ++qs) {
          s[kt][qs] = mfma16(kf0, qf[qs][0], s[kt][qs]);
          s[kt][qs] = mfma16(kf1, qf[qs][1], s[kt][qs]);
        }
      }
      __builtin_amdgcn_s_setprio(0);

      // causal mask + P = exp2(s) (q pre-scaled by 0.125*log2e).
      for (int qs = 0; qs < 2; ++qs) {
        float rs = 0.f;
        for (int kt = 0; kt < 4; ++kt)
          for (int r = 0; r < 4; ++r) {
            float v = s[kt][qs][r];
            if (maskt) {
              const int ka = k0 + kt * 16 + 4 * g + r;
              const int qa = q0 + qs * 16 + lrow;
              v = (ka <= qa) ? v : -INFINITY;
            }
            const float p = __builtin_amdgcn_exp2f(v);   // -inf -> 0
            s[kt][qs][r] = p;
            rs += p;
          }
        l_[qs] += rs;
      }

      // ---- P -> per-wave LDS (transpose to [q][k])
      for (int qs = 0; qs < 2; ++qs)
        for (int kt = 0; kt < 4; ++kt) {
          union { __bf16 h4[4]; unsigned long long u; } w;
          for (int r = 0; r < 4; ++r) w.h4[r] = (__bf16)(s[kt][qs][r]);
          *reinterpret_cast<unsigned long long*>(
              &plds[wave][qs][lrow][kt * 16 + 4 * g]) = w.u;
        }
      asm volatile("s_waitcnt lgkmcnt(0)" ::: "memory");

      // ---- PV (swapped): o[qs][dt] += mfma(V_frag, P_frag)
      __builtin_amdgcn_s_setprio(1);
      for (int kc = 0; kc < 2; ++kc) {
        const bf16x8 pf0 = load8(&plds[wave][0][lrow][kc * 32 + g * 8]);
        const bf16x8 pf1 = load8(&plds[wave][1][lrow][kc * 32 + g * 8]);
        for (int dt = 0; dt < 4; ++dt) {
          const bf16x8 vf =
              load8(&vbuf[cur][(dt * 16 + lrow) * 64 + ((kc * 4 + g) ^ swz) * 8]);
          o[0][dt] = mfma16(vf, pf0, o[0][dt]);
          o[1][dt] = mfma16(vf, pf1, o[1][dt]);
        }
      }
      __builtin_amdgcn_s_setprio(0);
    }
    __syncthreads();   // drains vmcnt (prefetch) + protects buffers
  }

  // ---- epilogue: reduce l across lanes, write partials o/l + (m=0, l)
  for (int qs = 0; qs < 2; ++qs) {
    float lv = l_[qs];
    lv += __shfl_xor(lv, 16);
    lv += __shfl_xor(lv, 32);
    l_[qs] = lv;
  }
  unsigned short* ol = &plds[wave][0][0][0];        // view as [32][72]
  for (int qs = 0; qs < 2; ++qs) {
    const float inv = 1.f / l_[qs];
    for (int dt = 0; dt < 4; ++dt) {
      union { __bf16 h4[4]; unsigned long long u; } w;
      for (int r = 0; r < 4; ++r) w.h4[r] = (__bf16)(o[qs][dt][r] * inv);
      *reinterpret_cast<unsigned long long*>(
          &ol[(qs * 16 + lrow) * 72 + dt * 16 + 4 * g]) = w.u;
    }
  }
  asm volatile("s_waitcnt lgkmcnt(0)" ::: "memory");
  for (int rr = 0; rr < 4; ++rr) {
    const int row = rr * 8 + (lane >> 3);
    const int cs = (lane & 7) * 8;
    const bf16x8 v = load8(&ol[row * 72 + cs]);
    *reinterpret_cast<bf16x8*>(
        &po[(size_t)slot * 8192 + (wave * 32 + row) * 64 + cs]) = v;
  }
  if (g == 0)
    for (int qs = 0; qs < 2; ++qs)
      pml[slot * 128 + wave * 32 + qs * 16 + lrow] = make_float2(0.f, l_[qs]);
}

// ---------------------------------------------------------------------------
// Combine: merge <=4 segment partials per (head, 128-q block) -> aout bf16
// ---------------------------------------------------------------------------
__global__ __launch_bounds__(256) void attn_combine_kernel(
    const unsigned short* __restrict__ po, const float2* __restrict__ pml,
    unsigned short* __restrict__ aout) {
  const int qg = blockIdx.x, h = blockIdx.y;
  const int nseg = (2 * qg + 9) / 8;
  const int tid = threadIdx.x;
  const int row = tid >> 1, c0 = (tid & 1) * 32;
  float L = 0.f, w[4];
  for (int s = 0; s < nseg; ++s) {
    const int slot = h * 40 + kQGF[qg][s];
    w[s] = pml[slot * 128 + row].y;     // m==0 everywhere -> weight = l
    L += w[s];
  }
  float acc[32] = {};
  for (int s = 0; s < nseg; ++s) {
    const int slot = h * 40 + kQGF[qg][s];
    const unsigned short* p = &po[(size_t)slot * 8192 + row * 64 + c0];
    for (int j = 0; j < 4; ++j) {
      const bf16x8 v = load8(p + j * 8);
      for (int e = 0; e < 8; ++e) acc[j * 8 + e] += w[s] * (float)v[e];
    }
  }
  const float invL = 1.f / L;
  for (int j = 0; j < 4; ++j) {
    __bf16 ov[8];
    for (int e = 0; e < 8; ++e) ov[e] = (__bf16)(acc[j * 8 + e] * invL);
    *reinterpret_cast<bf16x8*>(
        &aout[(size_t)(qg * 128 + row) * C_DIM + h * D_HEAD + c0 + j * 8]) =
        *reinterpret_cast<const bf16x8*>(ov);
  }
}

// ---------------------------------------------------------------------------
// GEMM3: out = attn_out(bf16) @ Wo. BM=64, BN=128 -> 512 blocks (grid fill).
// 2x2 waves, each 32x64. BK=64, XOR swizzle, bijective XCD swizzle.
// ---------------------------------------------------------------------------
__global__ __launch_bounds__(256, 2) void gemm3_kernel(
    const unsigned short* __restrict__ A, const unsigned short* __restrict__ BT,
    float* __restrict__ out) {
  __shared__ unsigned short As[64 * 64], Bs[128 * 64];
  const int tid = threadIdx.x;
  const int orig = (int)blockIdx.y * 16 + (int)blockIdx.x;   // 512 blocks
  const int wgid = (orig & 7) * 64 + (orig >> 3);            // bijective XCD swz
  const int n0 = (wgid % 16) * 128, m0 = (wgid / 16) * 64;
  const int lane = tid & 63, wave = tid >> 6;
  const int wm = wave >> 1, wn = wave & 1;
  const int lrow = lane & 15, g = lane >> 4;
  const int srow8 = lane >> 3, pchunk = lane & 7;
  const int swz = lrow & 7;
  f32x4 acc[2][4] = {};
  for (int kb = 0; kb < C_DIM; kb += 64) {
    __syncthreads();
    for (int p = 0; p < 2; ++p) {
      const int row = (p * 4 + wave) * 8 + srow8;
      const int gcol = (pchunk ^ srow8) * 8;
      GLOAD_LDS16(&A[(size_t)(m0 + row) * C_DIM + kb + gcol],
                  &As[row * 64 + pchunk * 8]);
    }
    for (int p = 0; p < 4; ++p) {
      const int row = (p * 4 + wave) * 8 + srow8;
      const int gcol = (pchunk ^ srow8) * 8;
      GLOAD_LDS16(&BT[(size_t)(n0 + row) * C_DIM + kb + gcol],
                  &Bs[row * 64 + pchunk * 8]);
    }
    __syncthreads();
    for (int kk = 0; kk < 2; ++kk) {
      bf16x8 af[2], bfr[4];
      const int cc = ((kk * 4 + g) ^ swz) * 8;
      for (int i = 0; i < 2; ++i)
        af[i] = load8(&As[(wm * 32 + i * 16 + lrow) * 64 + cc]);
      for (int i = 0; i < 4; ++i)
        bfr[i] = load8(&Bs[(wn * 64 + i * 16 + lrow) * 64 + cc]);
      for (int mi = 0; mi < 2; ++mi)
        for (int ni = 0; ni < 4; ++ni)
          acc[mi][ni] = mfma16(af[mi], bfr[ni], acc[mi][ni]);
    }
  }
  for (int mi = 0; mi < 2; ++mi)
    for (int ni = 0; ni < 4; ++ni)
      for (int r = 0; r < 4; ++r)
        out[(size_t)(m0 + wm * 32 + mi * 16 + g * 4 + r) * C_DIM +
            n0 + wn * 64 + ni * 16 + lrow] = acc[mi][ni][r];
}

// ---------------------------------------------------------------------------
extern "C" void kernel_launch(void* const* d_in, const int* in_sizes, int n_in,
                              void* d_out, int out_size, void* d_ws, size_t ws_size,
                              hipStream_t stream) {
  (void)in_sizes; (void)n_in; (void)out_size; (void)ws_size;
  const float* x    = (const float*)d_in[0];
  const float* cosb = (const float*)d_in[1];
  const float* sinb = (const float*)d_in[2];
  const float* Wqkv = (const float*)d_in[3];
  const float* Wo   = (const float*)d_in[4];
  float* out = (float*)d_out;

  unsigned short* WqkvT_hi = (unsigned short*)d_ws;                       // [3072][2048]
  unsigned short* WoT      = WqkvT_hi + (size_t)NQKV * C_DIM;             // [2048][2048]
  unsigned short* qkv      = WoT + (size_t)C_DIM * C_DIM;                 // [2048][3072]
  unsigned short* Vt       = qkv + (size_t)T_SEQ * NQKV;                  // [512][2048]
  unsigned short* aout     = Vt + (size_t)KVH_ * D_HEAD * T_SEQ;          // [2048][2048]
  unsigned short* Xh       = aout + (size_t)T_SEQ * C_DIM;                // [2048][2048]
  // Partials (attn runs after gemm1, so Xh and WqkvT_hi are dead then):
  unsigned short* po  = Xh;              // 1280 x 128 x 64 bf16 = 21.0 MB
  float2*         pml = (float2*)d_ws;   // 1280 x 128 float2 = 1.3 MB

  cast_x_kernel<<<(T_SEQ * C_DIM) / (256 * 8), 256, 0, stream>>>(x, Xh);
  transpose_cast_kernel<<<dim3(NQKV / 64, C_DIM / 64), 256, 0, stream>>>(
      Wqkv, WqkvT_hi, C_DIM, NQKV);
  transpose_cast_kernel<<<dim3(C_DIM / 64, C_DIM / 64), 256, 0, stream>>>(
      Wo, WoT, C_DIM, C_DIM);
  gemm1_kernel<<<dim3(24, 32), 256, 0, stream>>>(Xh, WqkvT_hi, cosb, sinb, qkv);
  vt_kernel<<<dim3(T_SEQ / 64, (KVH_ * D_HEAD) / 64), 256, 0, stream>>>(qkv, Vt);
  attn_seg_kernel<<<dim3(HQ, 40), 256, 0, stream>>>(qkv, Vt, po, pml);
  attn_combine_kernel<<<dim3(16, HQ), 256, 0, stream>>>(po, pml, aout);
  gemm3_kernel<<<dim3(16, 32), 256, 0, stream>>>(aout, WoT, out);
}

// Round 23
// 122.637 us; speedup vs baseline: 1.0978x; 1.0334x over previous
//
#include <hip/hip_runtime.h>
#include <hip/hip_bf16.h>
#include <cstdint>
#include <cstddef>

// Problem constants (B=1, T=2048, C=2048, H=32, KVH=8, D=64)
#define T_SEQ 2048
#define C_DIM 2048
#define NQKV  3072   // H*D + 2*KVH*D
#define HQ    32
#define KVH_  8
#define D_HEAD 64

using bf16x8 = __attribute__((ext_vector_type(8))) __bf16;
using f32x4  = __attribute__((ext_vector_type(4))) float;

typedef const __attribute__((address_space(1))) void* gas_ptr;
typedef __attribute__((address_space(3))) void* las_ptr;
#define GLOAD_LDS16(g, l) __builtin_amdgcn_global_load_lds((gas_ptr)(g), (las_ptr)(l), 16, 0, 0)

static __device__ __forceinline__ unsigned short f2bf(float f) {
  union { float f; unsigned int u; } v; v.f = f;
  unsigned int u = v.u;
  unsigned int r = u + 0x7fffu + ((u >> 16) & 1u);   // RNE
  return (unsigned short)(r >> 16);
}
static __device__ __forceinline__ float bf2f(unsigned short s) {
  union { unsigned int u; float f; } v; v.u = ((unsigned int)s) << 16;
  return v.f;
}
static __device__ __forceinline__ bf16x8 load8(const unsigned short* p) {
  return *reinterpret_cast<const bf16x8*>(p);
}
static __device__ __forceinline__ f32x4 mfma16(bf16x8 a, bf16x8 b, f32x4 c) {
  return __builtin_amdgcn_mfma_f32_16x16x32_bf16(a, b, c, 0, 0, 0);
}

// Heavy-first static schedule for attn split-K blocks (40 per head):
// f -> (qg, seg) sorted by tile count desc (27x8-tile, 4x6, 4x4, 5x2).
static __device__ const unsigned char kF2QG[40] = {
    15, 15, 15, 15, 14, 14, 14, 13, 13, 13, 12, 12, 12, 11, 11,
    10, 10, 9, 9, 8, 8, 7, 7, 6, 5, 4, 3,
    14, 11, 6, 2, 13, 10, 5, 1, 12, 9, 8, 4, 0};
static __device__ const unsigned char kF2SEG[40] = {
    0, 1, 2, 3, 0, 1, 2, 0, 1, 2, 0, 1, 2, 0, 1,
    0, 1, 0, 1, 0, 1, 0, 1, 0, 0, 0, 0,
    3, 2, 1, 0, 3, 2, 1, 0, 3, 2, 2, 1, 0};
// Inverse: qg -> f index of each of its segments.
static __device__ const unsigned char kQGF[16][4] = {
    {39, 0, 0, 0}, {34, 0, 0, 0}, {30, 0, 0, 0}, {26, 0, 0, 0},
    {25, 38, 0, 0}, {24, 33, 0, 0}, {23, 29, 0, 0}, {21, 22, 0, 0},
    {19, 20, 37, 0}, {17, 18, 36, 0}, {15, 16, 32, 0}, {13, 14, 28, 0},
    {10, 11, 12, 35}, {7, 8, 9, 31}, {4, 5, 6, 27}, {0, 1, 2, 3}};

// ---------------------------------------------------------------------------
// prep: ONE kernel for all preprocessing (overlapped HBM streams):
//   blocks [0, 2048)        : cast x f32 -> bf16 (8 elems/thread)
//   blocks [2048, 3584)     : transpose+cast Wqkv -> WqkvT [3072][2048]
//   blocks [3584, 4608)     : transpose+cast Wo   -> WoT   [2048][2048]
// ---------------------------------------------------------------------------
__global__ __launch_bounds__(256) void prep_kernel(
    const float* __restrict__ x, unsigned short* __restrict__ xh,
    const float* __restrict__ Wqkv, unsigned short* __restrict__ WqkvT,
    const float* __restrict__ Wo, unsigned short* __restrict__ WoT) {
  __shared__ float tile[64][65];
  int b = blockIdx.x;
  const int tid = threadIdx.x;
  if (b < 2048) {                     // ---- cast_x
    const int i = (b * 256 + tid) * 8;
    const float4 a = *reinterpret_cast<const float4*>(x + i);
    const float4 c = *reinterpret_cast<const float4*>(x + i + 4);
    ushort h[8];
    h[0] = f2bf(a.x); h[1] = f2bf(a.y); h[2] = f2bf(a.z); h[3] = f2bf(a.w);
    h[4] = f2bf(c.x); h[5] = f2bf(c.y); h[6] = f2bf(c.z); h[7] = f2bf(c.w);
    *reinterpret_cast<uint4*>(xh + i) = *reinterpret_cast<const uint4*>(h);
    return;
  }
  b -= 2048;
  const float* src;
  unsigned short* dst;
  int C, bx, by;
  if (b < 1536) {                     // ---- Wqkv transpose (48 x 32 tiles)
    src = Wqkv; dst = WqkvT; C = NQKV;
    bx = b % 48; by = b / 48;
  } else {                            // ---- Wo transpose (32 x 32 tiles)
    b -= 1536;
    src = Wo; dst = WoT; C = C_DIM;
    bx = b % 32; by = b / 32;
  }
  const int R = C_DIM;
  const int r0 = by * 64, c0 = bx * 64;
  const int lr = tid >> 4, lc = (tid & 15) * 4;
  for (int i = 0; i < 4; ++i) {
    const int row = lr + i * 16;
    const float4 v = *reinterpret_cast<const float4*>(&src[(size_t)(r0 + row) * C + c0 + lc]);
    tile[row][lc + 0] = v.x; tile[row][lc + 1] = v.y;
    tile[row][lc + 2] = v.z; tile[row][lc + 3] = v.w;
  }
  __syncthreads();
  for (int i = 0; i < 4; ++i) {
    const int n = lr + i * 16;
    ushort4 h;
    h.x = f2bf(tile[lc + 0][n]); h.y = f2bf(tile[lc + 1][n]);
    h.z = f2bf(tile[lc + 2][n]); h.w = f2bf(tile[lc + 3][n]);
    *reinterpret_cast<ushort4*>(&dst[(size_t)(c0 + n) * R + r0 + lc]) = h;
  }
}

// ---------------------------------------------------------------------------
// GEMM1: qkv = bf16(x) @ bf16(Wqkv). BM=64, BN=128 -> 768 blocks (grid fill).
// 2x2 waves, each 32x64 (full head per wave for RoPE). BK=64, XOR swizzle.
// Epilogue: RoPE; q pre-scaled by 0.125*log2(e) (exp2-fold).
// ---------------------------------------------------------------------------
__global__ __launch_bounds__(256, 2) void gemm1_kernel(
    const unsigned short* __restrict__ Xh, const unsigned short* __restrict__ BTh,
    const float* __restrict__ cosb, const float* __restrict__ sinb,
    unsigned short* __restrict__ qkv) {
  __shared__ unsigned short Ah[64 * 64], Bh[128 * 64];
  const int tid = threadIdx.x;
  const int orig = (int)blockIdx.y * 24 + (int)blockIdx.x;   // 768 blocks
  const int wgid = (orig & 7) * 96 + (orig >> 3);            // bijective XCD swz
  const int n0 = (wgid % 24) * 128, m0 = (wgid / 24) * 64;
  const int lane = tid & 63, wave = tid >> 6;
  const int wm = wave >> 1, wn = wave & 1;      // 2x2 waves, 32x64 per wave
  const int lrow = lane & 15, g = lane >> 4;
  const int srow8 = lane >> 3, pchunk = lane & 7;
  const int swz = lrow & 7;
  f32x4 acc[2][4] = {};
  for (int kb = 0; kb < C_DIM; kb += 64) {
    __syncthreads();
    for (int p = 0; p < 2; ++p) {               // A: 64 rows
      const int row = (p * 4 + wave) * 8 + srow8;
      const int gcol = (pchunk ^ srow8) * 8;
      GLOAD_LDS16(&Xh[(size_t)(m0 + row) * C_DIM + kb + gcol],
                  &Ah[row * 64 + pchunk * 8]);
    }
    for (int p = 0; p < 4; ++p) {               // B: 128 rows
      const int row = (p * 4 + wave) * 8 + srow8;
      const int gcol = (pchunk ^ srow8) * 8;
      GLOAD_LDS16(&BTh[(size_t)(n0 + row) * C_DIM + kb + gcol],
                  &Bh[row * 64 + pchunk * 8]);
    }
    __syncthreads();
    for (int kk = 0; kk < 2; ++kk) {
      bf16x8 ah[2], bh[4];
      const int cc = ((kk * 4 + g) ^ swz) * 8;
      for (int i = 0; i < 2; ++i)
        ah[i] = load8(&Ah[(wm * 32 + i * 16 + lrow) * 64 + cc]);
      for (int i = 0; i < 4; ++i)
        bh[i] = load8(&Bh[(wn * 64 + i * 16 + lrow) * 64 + cc]);
      for (int mi = 0; mi < 2; ++mi)
        for (int ni = 0; ni < 4; ++ni)
          acc[mi][ni] = mfma16(ah[mi], bh[ni], acc[mi][ni]);
    }
  }
  const int colbase = n0 + wn * 64;                 // 64-aligned => one head
  const bool isv = colbase >= (C_DIM + KVH_ * D_HEAD);
  // q scale folds softmax's 1/8 AND log2(e) so attn uses raw v_exp (base 2).
  const float qsc = (colbase < C_DIM) ? 0.18033688011112042f : 1.0f;
  for (int mi = 0; mi < 2; ++mi) {
    for (int r = 0; r < 4; ++r) {
      const int trow = m0 + wm * 32 + mi * 16 + g * 4 + r;
      if (!isv) {
        for (int ni = 0; ni < 2; ++ni) {
          const int dh = ni * 16 + lrow;            // 0..31
          const float c = cosb[trow * 32 + dh];
          const float s = sinb[trow * 32 + dh];
          const float a = bf2f(f2bf(acc[mi][ni][r]));       // ref: bf16 then f32 rope
          const float b = bf2f(f2bf(acc[mi][ni + 2][r]));
          qkv[(size_t)trow * NQKV + colbase + dh]      = f2bf((a * c - b * s) * qsc);
          qkv[(size_t)trow * NQKV + colbase + dh + 32] = f2bf((a * s + b * c) * qsc);
        }
      } else {
        for (int ni = 0; ni < 4; ++ni)
          qkv[(size_t)trow * NQKV + colbase + ni * 16 + lrow] = f2bf(acc[mi][ni][r]);
      }
    }
  }
}

// ---------------------------------------------------------------------------
// V transpose: Vt[kvh*64+d][t] = qkv[t][2560 + kvh*64 + d]
// ---------------------------------------------------------------------------
__global__ __launch_bounds__(256) void vt_kernel(const unsigned short* __restrict__ qkv,
                                                 unsigned short* __restrict__ vt) {
  __shared__ unsigned short tile[64][72];
  const int t0 = blockIdx.x * 64, j0 = blockIdx.y * 64;
  const int tid = threadIdx.x;
  const int lr = tid >> 4, lc = (tid & 15) * 4;
  for (int i = 0; i < 4; ++i) {
    const int row = lr + i * 16;
    const ushort4 v = *reinterpret_cast<const ushort4*>(
        &qkv[(size_t)(t0 + row) * NQKV + (C_DIM + KVH_ * D_HEAD) + j0 + lc]);
    *reinterpret_cast<ushort4*>(&tile[row][lc]) = v;
  }
  __syncthreads();
  for (int i = 0; i < 4; ++i) {
    const int j = lr + i * 16;
    ushort4 v;
    v.x = tile[lc + 0][j]; v.y = tile[lc + 1][j];
    v.z = tile[lc + 2][j]; v.w = tile[lc + 3][j];
    *reinterpret_cast<ushort4*>(&vt[(size_t)(j0 + j) * T_SEQ + t0 + lc]) = v;
  }
}

// ---------------------------------------------------------------------------
// Flash attention, split-K (round-22 kernel, best known):
// K,V dbuf LDS (KVBLK=64), fixed-reference softmax P=exp2(s), global
// heavy-first dispatch (f-major grid), deferred l-reduce.
// ---------------------------------------------------------------------------
__global__ __launch_bounds__(256, 3) void attn_seg_kernel(
    const unsigned short* __restrict__ qkv, const unsigned short* __restrict__ Vt,
    unsigned short* __restrict__ po, float2* __restrict__ pml) {
  __shared__ unsigned short kbuf[2][64 * 64];     // [buf][row k][d] (chunk-swz)
  __shared__ unsigned short vbuf[2][64 * 64];     // [buf][row d][t] (chunk-swz)
  __shared__ unsigned short plds[4][2][16][72];   // [wave][qs][q-row][64k + pad]
  const int h = blockIdx.x, f = blockIdx.y;       // f-major dispatch (heavy 1st)
  const int qg = kF2QG[f];
  const int seg = kF2SEG[f];
  const int slot = h * 40 + f;
  const int tid = threadIdx.x;
  const int wave = tid >> 6, lane = tid & 63;
  const int kvh = h >> 2;
  const int q0b = qg * 128;
  const int q0 = q0b + wave * 32;
  const int lrow = lane & 15, g = lane >> 4;

  const int t0 = seg * 8;
  const int t1 = min(t0 + 8, 2 * qg + 2);         // tiles [t0, t1)

  const int srow = lane >> 3;                     // row within 8-row group
  const int schunk = (lane & 7) ^ srow;           // pre-swizzled source chunk
  const unsigned short* Kg = qkv + C_DIM + kvh * D_HEAD;

  bf16x8 qf[2][2];
  for (int qs = 0; qs < 2; ++qs)
    for (int dc = 0; dc < 2; ++dc)
      qf[qs][dc] = load8(&qkv[(size_t)(q0 + qs * 16 + lrow) * NQKV + h * D_HEAD + dc * 32 + g * 8]);

  f32x4 o[2][4] = {};                 // [qs][dt]: rows=d (4g+r), cols=q (lrow)
  float l_[2] = {0.f, 0.f};           // lane-local partial (reduced at epilogue)
  const int swz = (lrow & 7);         // read-side chunk swizzle

  {
    const int k00 = t0 * 64;
    for (int j = 0; j < 2; ++j) {
      const int r0 = wave * 16 + j * 8;
      GLOAD_LDS16(Kg + (size_t)(k00 + r0 + srow) * NQKV + schunk * 8,
                  &kbuf[0][r0 * 64 + lane * 8]);
      GLOAD_LDS16(Vt + (size_t)(kvh * 64 + r0 + srow) * T_SEQ + k00 + schunk * 8,
                  &vbuf[0][r0 * 64 + lane * 8]);
    }
  }
  __syncthreads();

  for (int t = t0; t < t1; ++t) {
    const int cur = (t - t0) & 1;
    const int k0 = t * 64;
    if (t + 1 < t1) {
      const int k0n = k0 + 64;
      for (int j = 0; j < 2; ++j) {
        const int r0 = wave * 16 + j * 8;
        GLOAD_LDS16(Kg + (size_t)(k0n + r0 + srow) * NQKV + schunk * 8,
                    &kbuf[cur ^ 1][r0 * 64 + lane * 8]);
        GLOAD_LDS16(Vt + (size_t)(kvh * 64 + r0 + srow) * T_SEQ + k0n + schunk * 8,
                    &vbuf[cur ^ 1][r0 * 64 + lane * 8]);
      }
    }

    if (k0 <= q0 + 31) {              // causal: skip fully-masked tiles
      const bool maskt = (k0 + 63 > q0);

      f32x4 s[4][2] = {};
      __builtin_amdgcn_s_setprio(1);
      for (int kt = 0; kt < 4; ++kt) {
        const unsigned short* krow = &kbuf[cur][(kt * 16 + lrow) * 64];
        const bf16x8 kf0 = load8(krow + ((0 * 4 + g) ^ swz) * 8);
        const bf16x8 kf1 = load8(krow + ((1 * 4 + g) ^ swz) * 8);
        for (int qs = 0; qs < 2; ++qs) {
          s[kt][qs] = mfma16(kf0, qf[qs][0], s[kt][qs]);
          s[kt][qs] = mfma16(kf1, qf[qs][1], s[kt][qs]);
        }
      }
      __builtin_amdgcn_s_setprio(0);

      // causal mask + P = exp2(s) (q pre-scaled by 0.125*log2e).
      for (int qs = 0; qs < 2; ++qs) {
        float rs = 0.f;
        for (int kt = 0; kt < 4; ++kt)
          for (int r = 0; r < 4; ++r) {
            float v = s[kt][qs][r];
            if (maskt) {
              const int ka = k0 + kt * 16 + 4 * g + r;
              const int qa = q0 + qs * 16 + lrow;
              v = (ka <= qa) ? v : -INFINITY;
            }
            const float p = __builtin_amdgcn_exp2f(v);   // -inf -> 0
            s[kt][qs][r] = p;
            rs += p;
          }
        l_[qs] += rs;
      }

      // ---- P -> per-wave LDS (transpose to [q][k])
      for (int qs = 0; qs < 2; ++qs)
        for (int kt = 0; kt < 4; ++kt) {
          union { __bf16 h4[4]; unsigned long long u; } w;
          for (int r = 0; r < 4; ++r) w.h4[r] = (__bf16)(s[kt][qs][r]);
          *reinterpret_cast<unsigned long long*>(
              &plds[wave][qs][lrow][kt * 16 + 4 * g]) = w.u;
        }
      asm volatile("s_waitcnt lgkmcnt(0)" ::: "memory");

      // ---- PV (swapped): o[qs][dt] += mfma(V_frag, P_frag)
      __builtin_amdgcn_s_setprio(1);
      for (int kc = 0; kc < 2; ++kc) {
        const bf16x8 pf0 = load8(&plds[wave][0][lrow][kc * 32 + g * 8]);
        const bf16x8 pf1 = load8(&plds[wave][1][lrow][kc * 32 + g * 8]);
        for (int dt = 0; dt < 4; ++dt) {
          const bf16x8 vf =
              load8(&vbuf[cur][(dt * 16 + lrow) * 64 + ((kc * 4 + g) ^ swz) * 8]);
          o[0][dt] = mfma16(vf, pf0, o[0][dt]);
          o[1][dt] = mfma16(vf, pf1, o[1][dt]);
        }
      }
      __builtin_amdgcn_s_setprio(0);
    }
    __syncthreads();   // drains vmcnt (prefetch) + protects buffers
  }

  // ---- epilogue: reduce l across lanes, write partials o/l + (m=0, l)
  for (int qs = 0; qs < 2; ++qs) {
    float lv = l_[qs];
    lv += __shfl_xor(lv, 16);
    lv += __shfl_xor(lv, 32);
    l_[qs] = lv;
  }
  unsigned short* ol = &plds[wave][0][0][0];        // view as [32][72]
  for (int qs = 0; qs < 2; ++qs) {
    const float inv = 1.f / l_[qs];
    for (int dt = 0; dt < 4; ++dt) {
      union { __bf16 h4[4]; unsigned long long u; } w;
      for (int r = 0; r < 4; ++r) w.h4[r] = (__bf16)(o[qs][dt][r] * inv);
      *reinterpret_cast<unsigned long long*>(
          &ol[(qs * 16 + lrow) * 72 + dt * 16 + 4 * g]) = w.u;
    }
  }
  asm volatile("s_waitcnt lgkmcnt(0)" ::: "memory");
  for (int rr = 0; rr < 4; ++rr) {
    const int row = rr * 8 + (lane >> 3);
    const int cs = (lane & 7) * 8;
    const bf16x8 v = load8(&ol[row * 72 + cs]);
    *reinterpret_cast<bf16x8*>(
        &po[(size_t)slot * 8192 + (wave * 32 + row) * 64 + cs]) = v;
  }
  if (g == 0)
    for (int qs = 0; qs < 2; ++qs)
      pml[slot * 128 + wave * 32 + qs * 16 + lrow] = make_float2(0.f, l_[qs]);
}

// ---------------------------------------------------------------------------
// Combine: merge <=4 segment partials per (head, 128-q block) -> aout bf16
// ---------------------------------------------------------------------------
__global__ __launch_bounds__(256) void attn_combine_kernel(
    const unsigned short* __restrict__ po, const float2* __restrict__ pml,
    unsigned short* __restrict__ aout) {
  const int qg = blockIdx.x, h = blockIdx.y;
  const int nseg = (2 * qg + 9) / 8;
  const int tid = threadIdx.x;
  const int row = tid >> 1, c0 = (tid & 1) * 32;
  float L = 0.f, w[4];
  for (int s = 0; s < nseg; ++s) {
    const int slot = h * 40 + kQGF[qg][s];
    w[s] = pml[slot * 128 + row].y;     // m==0 everywhere -> weight = l
    L += w[s];
  }
  float acc[32] = {};
  for (int s = 0; s < nseg; ++s) {
    const int slot = h * 40 + kQGF[qg][s];
    const unsigned short* p = &po[(size_t)slot * 8192 + row * 64 + c0];
    for (int j = 0; j < 4; ++j) {
      const bf16x8 v = load8(p + j * 8);
      for (int e = 0; e < 8; ++e) acc[j * 8 + e] += w[s] * (float)v[e];
    }
  }
  const float invL = 1.f / L;
  for (int j = 0; j < 4; ++j) {
    __bf16 ov[8];
    for (int e = 0; e < 8; ++e) ov[e] = (__bf16)(acc[j * 8 + e] * invL);
    *reinterpret_cast<bf16x8*>(
        &aout[(size_t)(qg * 128 + row) * C_DIM + h * D_HEAD + c0 + j * 8]) =
        *reinterpret_cast<const bf16x8*>(ov);
  }
}

// ---------------------------------------------------------------------------
// GEMM3: out = attn_out(bf16) @ Wo. BM=64, BN=128 -> 512 blocks (grid fill).
// 2x2 waves, each 32x64. BK=64, XOR swizzle, bijective XCD swizzle.
// ---------------------------------------------------------------------------
__global__ __launch_bounds__(256, 2) void gemm3_kernel(
    const unsigned short* __restrict__ A, const unsigned short* __restrict__ BT,
    float* __restrict__ out) {
  __shared__ unsigned short As[64 * 64], Bs[128 * 64];
  const int tid = threadIdx.x;
  const int orig = (int)blockIdx.y * 16 + (int)blockIdx.x;   // 512 blocks
  const int wgid = (orig & 7) * 64 + (orig >> 3);            // bijective XCD swz
  const int n0 = (wgid % 16) * 128, m0 = (wgid / 16) * 64;
  const int lane = tid & 63, wave = tid >> 6;
  const int wm = wave >> 1, wn = wave & 1;
  const int lrow = lane & 15, g = lane >> 4;
  const int srow8 = lane >> 3, pchunk = lane & 7;
  const int swz = lrow & 7;
  f32x4 acc[2][4] = {};
  for (int kb = 0; kb < C_DIM; kb += 64) {
    __syncthreads();
    for (int p = 0; p < 2; ++p) {
      const int row = (p * 4 + wave) * 8 + srow8;
      const int gcol = (pchunk ^ srow8) * 8;
      GLOAD_LDS16(&A[(size_t)(m0 + row) * C_DIM + kb + gcol],
                  &As[row * 64 + pchunk * 8]);
    }
    for (int p = 0; p < 4; ++p) {
      const int row = (p * 4 + wave) * 8 + srow8;
      const int gcol = (pchunk ^ srow8) * 8;
      GLOAD_LDS16(&BT[(size_t)(n0 + row) * C_DIM + kb + gcol],
                  &Bs[row * 64 + pchunk * 8]);
    }
    __syncthreads();
    for (int kk = 0; kk < 2; ++kk) {
      bf16x8 af[2], bfr[4];
      const int cc = ((kk * 4 + g) ^ swz) * 8;
      for (int i = 0; i < 2; ++i)
        af[i] = load8(&As[(wm * 32 + i * 16 + lrow) * 64 + cc]);
      for (int i = 0; i < 4; ++i)
        bfr[i] = load8(&Bs[(wn * 64 + i * 16 + lrow) * 64 + cc]);
      for (int mi = 0; mi < 2; ++mi)
        for (int ni = 0; ni < 4; ++ni)
          acc[mi][ni] = mfma16(af[mi], bfr[ni], acc[mi][ni]);
    }
  }
  for (int mi = 0; mi < 2; ++mi)
    for (int ni = 0; ni < 4; ++ni)
      for (int r = 0; r < 4; ++r)
        out[(size_t)(m0 + wm * 32 + mi * 16 + g * 4 + r) * C_DIM +
            n0 + wn * 64 + ni * 16 + lrow] = acc[mi][ni][r];
}

// ---------------------------------------------------------------------------
extern "C" void kernel_launch(void* const* d_in, const int* in_sizes, int n_in,
                              void* d_out, int out_size, void* d_ws, size_t ws_size,
                              hipStream_t stream) {
  (void)in_sizes; (void)n_in; (void)out_size; (void)ws_size;
  const float* x    = (const float*)d_in[0];
  const float* cosb = (const float*)d_in[1];
  const float* sinb = (const float*)d_in[2];
  const float* Wqkv = (const float*)d_in[3];
  const float* Wo   = (const float*)d_in[4];
  float* out = (float*)d_out;

  unsigned short* WqkvT_hi = (unsigned short*)d_ws;                       // [3072][2048]
  unsigned short* WoT      = WqkvT_hi + (size_t)NQKV * C_DIM;             // [2048][2048]
  unsigned short* qkv      = WoT + (size_t)C_DIM * C_DIM;                 // [2048][3072]
  unsigned short* Vt       = qkv + (size_t)T_SEQ * NQKV;                  // [512][2048]
  unsigned short* aout     = Vt + (size_t)KVH_ * D_HEAD * T_SEQ;          // [2048][2048]
  unsigned short* Xh       = aout + (size_t)T_SEQ * C_DIM;                // [2048][2048]
  // Partials (attn runs after gemm1, so Xh and WqkvT_hi are dead then):
  unsigned short* po  = Xh;              // 1280 x 128 x 64 bf16 = 21.0 MB
  float2*         pml = (float2*)d_ws;   // 1280 x 128 float2 = 1.3 MB

  prep_kernel<<<4608, 256, 0, stream>>>(x, Xh, Wqkv, WqkvT_hi, Wo, WoT);
  gemm1_kernel<<<dim3(24, 32), 256, 0, stream>>>(Xh, WqkvT_hi, cosb, sinb, qkv);
  vt_kernel<<<dim3(T_SEQ / 64, (KVH_ * D_HEAD) / 64), 256, 0, stream>>>(qkv, Vt);
  attn_seg_kernel<<<dim3(HQ, 40), 256, 0, stream>>>(qkv, Vt, po, pml);
  attn_combine_kernel<<<dim3(16, HQ), 256, 0, stream>>>(po, pml, aout);
  gemm3_kernel<<<dim3(16, 32), 256, 0, stream>>>(aout, WoT, out);
}